// Round 7
// baseline (1344.236 us; speedup 1.0000x reference)
//
#include <hip/hip_runtime.h>

#define N 8192
#define D 512
#define KNN 15
#define NPAIR 105
#define EPSF 1e-8f

#define RB 32
#define CB 64
#define KB 32

#define INF __int_as_float(0x7f800000)

typedef __attribute__((ext_vector_type(4))) float f32x4;
typedef __attribute__((ext_vector_type(8))) short s16x8;
typedef __attribute__((ext_vector_type(8))) unsigned short u16x8;
typedef unsigned long long u64;

typedef const unsigned int __attribute__((address_space(1)))* gp_t;
typedef unsigned int __attribute__((address_space(3)))* lp_t;

__device__ __forceinline__ void gl_lds16(const void* g, void* l) {
  __builtin_amdgcn_global_load_lds((gp_t)g, (lp_t)l, 16, 0, 0);
}

__device__ __forceinline__ unsigned short bf16_rne(float x) {
  unsigned int u = __float_as_uint(x);
  return (unsigned short)((u + 0x7fffu + ((u >> 16) & 1u)) >> 16);
}

#define VMCNT0 asm volatile("s_waitcnt vmcnt(0)" ::: "memory")
#define CFENCE asm volatile("" ::: "memory")

// ---------------------------------------------------------------- sq norms
__global__ __launch_bounds__(256)
void k_sqnorm(const float* __restrict__ A, const float* __restrict__ B,
              float* __restrict__ sq)
{
  int tid = threadIdx.x;
  int lane = tid & 63;
  int row = blockIdx.x * 4 + (tid >> 6);          // 0 .. 2N-1
  const float* src = (row < N) ? (A + (size_t)row * D)
                               : (B + (size_t)(row - N) * D);
  const float4* s4 = (const float4*)src + lane * 2;
  float4 x0 = s4[0], x1 = s4[1];
  float s = x0.x*x0.x + x0.y*x0.y + x0.z*x0.z + x0.w*x0.w
          + x1.x*x1.x + x1.y*x1.y + x1.z*x1.z + x1.w*x1.w;
#pragma unroll
  for (int o = 32; o; o >>= 1) s += __shfl_xor(s, o);
  if (lane == 0) sq[row] = s;
}

// ---------------------------------------------------------------- bf16 hi/lo split
__global__ __launch_bounds__(256)
void k_split(const float* __restrict__ A, const float* __restrict__ B,
             unsigned short* __restrict__ hi, unsigned short* __restrict__ lo)
{
  size_t t = (size_t)blockIdx.x * 256 + threadIdx.x;
  size_t base = t * 8;
  const float* src = (base < (size_t)N * D) ? (A + base) : (B + (base - (size_t)N * D));
  float4 x0 = ((const float4*)src)[0];
  float4 x1 = ((const float4*)src)[1];
  float xs[8] = {x0.x, x0.y, x0.z, x0.w, x1.x, x1.y, x1.z, x1.w};
  u16x8 hv, lv;
#pragma unroll
  for (int j = 0; j < 8; ++j) {
    unsigned short h = bf16_rne(xs[j]);
    float hf = __uint_as_float(((unsigned int)h) << 16);
    hv[j] = h;
    lv[j] = bf16_rne(xs[j] - hf);
  }
  *(u16x8*)(hi + base) = hv;
  *(u16x8*)(lo + base) = lv;
}

// ================================================================ 256^2-tile
// 8-wave phase-split MFMA gram + fused top-15 partials.
// LDS: dbuf 2 x 64KB at [0,131072): per buf Ahi[0,16K) Alo[16K,32K)
//      Bhi[32K,48K) Blo[48K,64K), each 256 rows x 64B (32 bf16 of k).
// Epilogue overlays Dt[256][128] f32 (XOR-swizzled) on [0,131072);
// merge overlays SV/SI; sqc at [131072,132096).
// Swizzle contract (rule 21): store chunk q of row r at mem chunk q^(r&7);
// scan reads mem chunk s^(srow&7) which holds logical chunk q == s.
__global__ __launch_bounds__(512, 2)
void k_knn8(const unsigned short* __restrict__ hi, const unsigned short* __restrict__ lo,
            const float* __restrict__ sqall,
            float* __restrict__ pval, int* __restrict__ pidx)
{
  __shared__ __align__(16) char smem[132096];
  float* sqc_l = (float*)(smem + 131072);
  float* SV = (float*)smem;                 // [256][30] f32 overlay (merge)
  int*   SI = (int*)(smem + 32768);         // [256][30] i32 overlay (merge)

  const int tid = threadIdx.x;
  const int lane = tid & 63, w = tid >> 6;  // 8 waves
  const int wr = w >> 2, wc = w & 3;        // 2 x 4 wave grid
  const int fr = lane & 15, fq = lane >> 4;
  const int sgx = fq ^ ((fr >> 1) & 3);     // read-side seg swizzle

  const int bi = blockIdx.x, split = blockIdx.y, which = blockIdx.z;
  const int row0 = bi * 256;
  const size_t mbase = (size_t)which * N * D;
  const unsigned short* Hi = hi + mbase;
  const unsigned short* Lo = lo + mbase;
  const float* sq = sqall + which * N;

  // staging: thread -> chunk (row rr, seg); source seg pre-swizzled, LDS linear
  const int rr = tid >> 2, sseg = tid & 3;
  const int ssg = sseg ^ ((rr >> 1) & 3);
  const unsigned short* pAh = Hi + (size_t)(row0 + rr) * D + ssg * 8;
  const unsigned short* pAl = Lo + (size_t)(row0 + rr) * D + ssg * 8;
  const unsigned short* pBh = Hi + (size_t)(split * 2048 + rr) * D + ssg * 8;
  const unsigned short* pBl = Lo + (size_t)(split * 2048 + rr) * D + ssg * 8;
  char* const dA = smem + (w << 10);        // wave-uniform dest base

#define STAGE8(nb) do{ char* d_ = dA + ((nb) << 16);                       \
    gl_lds16(pAh, d_);           gl_lds16(pAh + 65536, d_ + 8192);         \
    gl_lds16(pAl, d_ + 16384);   gl_lds16(pAl + 65536, d_ + 24576);        \
    gl_lds16(pBh, d_ + 32768);   gl_lds16(pBh + 65536, d_ + 40960);        \
    gl_lds16(pBl, d_ + 49152);   gl_lds16(pBl + 65536, d_ + 57344);        \
    pAh += 32; pAl += 32; pBh += 32; pBl += 32; }while(0)

  // scanner state (2 threads per row)
  const int srow = tid >> 1, ssub = tid & 1;
  const int grow = row0 + srow;
  const float sqr_t = sq[grow];
  float tv[KNN]; int ti[KNN];
#pragma unroll
  for (int j = 0; j < KNN; ++j) { tv[j] = INF; ti[j] = -1; }

  f32x4 acc[8][4];
  s16x8 ah[4], al[4], bh[2], bl[2];

#define PH(cbexp, MH, NH, RDA, STG, WV) do{                                   \
    const int cb_ = (cbexp);                                                  \
    const short* Sb_ = (const short*)(smem + (cb_ << 16));                    \
    if (RDA) {                                                                \
      _Pragma("unroll") for (int mm = 0; mm < 4; ++mm) {                      \
        const int off = (wr*128 + ((MH)*4+mm)*16 + fr)*32 + sgx*8;            \
        ah[mm] = *(const s16x8*)(Sb_ + off);                                  \
        al[mm] = *(const s16x8*)(Sb_ + 8192 + off);                           \
      }                                                                       \
    }                                                                         \
    { _Pragma("unroll") for (int nn = 0; nn < 2; ++nn) {                      \
        const int off = (wc*64 + ((NH)*2+nn)*16 + fr)*32 + sgx*8;             \
        bh[nn] = *(const s16x8*)(Sb_ + 16384 + off);                          \
        bl[nn] = *(const s16x8*)(Sb_ + 24576 + off);                          \
    } }                                                                       \
    if (STG) STAGE8(cb_ ^ 1);                                                 \
    if (WV) VMCNT0;                                                           \
    CFENCE; __builtin_amdgcn_s_barrier(); CFENCE;                             \
    __builtin_amdgcn_s_setprio(1);                                            \
    _Pragma("unroll") for (int mm = 0; mm < 4; ++mm)                          \
    _Pragma("unroll") for (int nn = 0; nn < 2; ++nn) {                        \
      f32x4 a_ = acc[(MH)*4+mm][(NH)*2+nn];                                   \
      a_ = __builtin_amdgcn_mfma_f32_16x16x32_bf16(ah[mm], bh[nn], a_, 0,0,0);\
      a_ = __builtin_amdgcn_mfma_f32_16x16x32_bf16(ah[mm], bl[nn], a_, 0,0,0);\
      a_ = __builtin_amdgcn_mfma_f32_16x16x32_bf16(al[mm], bh[nn], a_, 0,0,0);\
      acc[(MH)*4+mm][(NH)*2+nn] = a_;                                         \
    }                                                                         \
    __builtin_amdgcn_s_setprio(0);                                            \
    CFENCE; __builtin_amdgcn_s_barrier(); CFENCE;                             \
  }while(0)

  auto dt_write = [&](int h) {
    if ((wc >> 1) != h) return;
#pragma unroll
    for (int m = 0; m < 8; ++m)
#pragma unroll
      for (int j = 0; j < 4; ++j) {
        const int r = wr * 128 + m * 16 + fq * 4 + j;
        const int xr = (r & 7) << 4;
        char* rowb = smem + r * 512;
#pragma unroll
        for (int n = 0; n < 4; ++n) {
          const int cl4 = (((wc & 1) * 64 + n * 16 + fr)) * 4;
          *(float*)(rowb + (cl4 ^ xr)) = acc[m][n][j];   // raw dot
        }
      }
  };

  auto dt_scan = [&](int h, int ct) {
    float kth = tv[KNN - 1];
#pragma unroll 4
    for (int k = 0; k < 16; ++k) {
      const int s = ssub * 16 + k;
      // mem chunk s^(srow&7) holds logical chunk q == s (see contract above)
      const f32x4 dv = *(const f32x4*)(smem + srow * 512 + ((s * 16) ^ ((srow & 7) << 4)));
#pragma unroll
      for (int i = 0; i < 4; ++i) {
        const int cl = s * 4 + i;
        const int gcol = ct + h * 128 + cl;
        float d2 = fmaf(-2.0f, dv[i], sqr_t + sqc_l[h * 128 + cl]);
        if (gcol == grow) d2 = INF;
        if (d2 < kth) {
          const int gi = gcol;
#pragma unroll
          for (int jq = KNN - 1; jq >= 1; --jq) {
            const bool ja = (tv[jq] > d2), jb = (tv[jq - 1] > d2);
            const float nv = jb ? tv[jq - 1] : (ja ? d2 : tv[jq]);
            const int ni = jb ? ti[jq - 1] : (ja ? gi : ti[jq]);
            tv[jq] = nv; ti[jq] = ni;
          }
          if (tv[0] > d2) { tv[0] = d2; ti[0] = gi; }
          kth = tv[KNN - 1];
        }
      }
    }
  };

#pragma unroll 1
  for (int ci = 0; ci < 8; ++ci) {
    const int ct = split * 2048 + ci * 256;
#pragma unroll
    for (int m = 0; m < 8; ++m)
#pragma unroll
      for (int n = 0; n < 4; ++n) acc[m][n] = (f32x4){0.f, 0.f, 0.f, 0.f};

    // prologue: stage tile 0 into buf0
    STAGE8(0);
    VMCNT0; CFENCE; __builtin_amdgcn_s_barrier(); CFENCE;

#pragma unroll 1
    for (int t = 0; t < 15; ++t) {
      const int cb = t & 1;
      PH(cb, 0, 0, true,  true,  false);   // read a(mh0); stage next tile
      PH(cb, 0, 1, false, false, false);   // reuse a(mh0)
      PH(cb, 1, 0, true,  false, false);   // read a(mh1)
      PH(cb, 1, 1, false, false, true);    // drain: next-tile loads landed
    }
    // tail tile t=15 (buf1, no staging)
    PH(1, 0, 0, true,  false, false);
    PH(1, 0, 1, false, false, false);
    PH(1, 1, 0, true,  false, false);
    PH(1, 1, 1, false, false, false);

    // pointers: rewind A over K (=D), advance B by 256 rows minus K rewind
    pAh -= 512; pAl -= 512; pBh += 130560; pBl += 130560;

    // ---- epilogue (stage buffers dead; Dt overlays them)
    if (tid < 256) sqc_l[tid] = sq[ct + tid];
    dt_write(0);
    CFENCE; __syncthreads();
    dt_scan(0, ct);
    CFENCE; __syncthreads();
    dt_write(1);
    CFENCE; __syncthreads();
    dt_scan(1, ct);
    CFENCE; __syncthreads();
  }

  // ---- block end: merge the 2 scanner lists per row, write partials
#pragma unroll
  for (int j = 0; j < KNN; ++j) {
    SV[srow * 30 + ssub * 15 + j] = tv[j];
    SI[srow * 30 + ssub * 15 + j] = ti[j];
  }
  __syncthreads();
  if (tid < 256) {
    const int gr = row0 + tid;
    const size_t pb = (((size_t)which * 4 + split) * N + gr) * KNN;
    int p0 = 0, p1 = 0;
#pragma unroll
    for (int j = 0; j < KNN; ++j) {
      const float v0 = (p0 < KNN) ? SV[tid * 30 + p0] : INF;
      const float v1 = (p1 < KNN) ? SV[tid * 30 + 15 + p1] : INF;
      const int i0 = (p0 < KNN) ? SI[tid * 30 + p0] : 0x7fffffff;
      const int i1 = (p1 < KNN) ? SI[tid * 30 + 15 + p1] : 0x7fffffff;
      const bool t0 = (v0 < v1) || (v0 == v1 && i0 < i1);
      const float dvx = t0 ? v0 : v1;
      const int dix = t0 ? i0 : i1;
      if (t0) ++p0; else ++p1;
      pval[pb + j] = (dvx > 0.f) ? sqrtf(fmaxf(dvx, 1e-24f)) : 0.f;
      pidx[pb + j] = dix;
    }
  }
#undef PH
#undef STAGE8
}

// ---------------------------------------------------------------- 4-way merge of split partials
__global__ __launch_bounds__(256)
void k_merge(const float* __restrict__ pval, const int* __restrict__ pidx,
             float* __restrict__ knnd, int* __restrict__ knni)
{
  const int flat = blockIdx.x * 256 + threadIdx.x;
  const int which = flat >> 13, row = flat & (N - 1);
  const size_t b0 = (((size_t)which * 4 + 0) * N + row) * KNN;
  const size_t b1 = (((size_t)which * 4 + 1) * N + row) * KNN;
  const size_t b2 = (((size_t)which * 4 + 2) * N + row) * KNN;
  const size_t b3 = (((size_t)which * 4 + 3) * N + row) * KNN;
  float v0 = pval[b0], v1 = pval[b1], v2 = pval[b2], v3 = pval[b3];
  int i0 = pidx[b0], i1 = pidx[b1], i2 = pidx[b2], i3 = pidx[b3];
  int p0 = 0, p1 = 0, p2 = 0, p3 = 0;
  const size_t ob = ((size_t)which * N + row) * KNN;
#pragma unroll 1
  for (int j = 0; j < KNN; ++j) {
    const bool a01 = (v0 < v1) || (v0 == v1 && i0 < i1);
    const float va = a01 ? v0 : v1; const int ia = a01 ? i0 : i1;
    const bool a23 = (v2 < v3) || (v2 == v3 && i2 < i3);
    const float vb = a23 ? v2 : v3; const int ib = a23 ? i2 : i3;
    const bool ab = (va < vb) || (va == vb && ia < ib);
    knnd[ob + j] = ab ? va : vb;
    knni[ob + j] = ab ? ia : ib;
    if (ab) {
      if (a01) { ++p0; v0 = (p0 < KNN) ? pval[b0 + p0] : INF; i0 = (p0 < KNN) ? pidx[b0 + p0] : 0x7fffffff; }
      else     { ++p1; v1 = (p1 < KNN) ? pval[b1 + p1] : INF; i1 = (p1 < KNN) ? pidx[b1 + p1] : 0x7fffffff; }
    } else {
      if (a23) { ++p2; v2 = (p2 < KNN) ? pval[b2 + p2] : INF; i2 = (p2 < KNN) ? pidx[b2 + p2] : 0x7fffffff; }
      else     { ++p3; v3 = (p3 < KNN) ? pval[b3 + p3] : INF; i3 = (p3 < KNN) ? pidx[b3 + p3] : 0x7fffffff; }
    }
  }
}

// ---------------------------------------------------------------- fallback: f32 VALU gram KNN
__global__ __launch_bounds__(256)
void k_knn_fb(const float* __restrict__ Ecur, const float* __restrict__ Eref,
              const float* __restrict__ sqall,
              float* __restrict__ knnd, int* __restrict__ knni)
{
  const int which = blockIdx.y;
  const float* E = which ? Eref : Ecur;
  const float* sq = sqall + which * N;
  float* outd = knnd + (size_t)which * N * KNN;
  int* outi = knni + (size_t)which * N * KNN;
  const int row0 = blockIdx.x * RB;

  __shared__ float As[RB][KB + 1];
  __shared__ float Bs[KB][CB + 4];
  __shared__ float Dtf[RB][CB + 1];
  __shared__ float topv[RB][KNN];
  __shared__ int topi[RB][KNN];

  const int tid = threadIdx.x;
  const int tx = tid & 15, ty = tid >> 4;

  if (tid < RB) {
#pragma unroll
    for (int j = 0; j < KNN; ++j) { topv[tid][j] = INF; topi[tid][j] = -1; }
  }

  for (int ct = 0; ct < N; ct += CB) {
    float acc[2][4] = {{0.f,0.f,0.f,0.f},{0.f,0.f,0.f,0.f}};
    for (int kt = 0; kt < D; kt += KB) {
      __syncthreads();
      {
        int r = tid >> 3, c4 = (tid & 7) << 2;
        const float4 v = *(const float4*)&E[(size_t)(row0 + r) * D + kt + c4];
        As[r][c4+0] = v.x; As[r][c4+1] = v.y; As[r][c4+2] = v.z; As[r][c4+3] = v.w;
      }
      {
        int k = tid & 31, cbase = tid >> 5;
#pragma unroll
        for (int i = 0; i < 8; ++i) {
          int c = cbase + (i << 3);
          Bs[k][c] = E[(size_t)(ct + c) * D + kt + k];
        }
      }
      __syncthreads();
#pragma unroll
      for (int k = 0; k < KB; ++k) {
        float a0 = As[2*ty + 0][k], a1 = As[2*ty + 1][k];
        float4 b = *(const float4*)&Bs[k][tx << 2];
        acc[0][0] = fmaf(a0, b.x, acc[0][0]); acc[0][1] = fmaf(a0, b.y, acc[0][1]);
        acc[0][2] = fmaf(a0, b.z, acc[0][2]); acc[0][3] = fmaf(a0, b.w, acc[0][3]);
        acc[1][0] = fmaf(a1, b.x, acc[1][0]); acc[1][1] = fmaf(a1, b.y, acc[1][1]);
        acc[1][2] = fmaf(a1, b.z, acc[1][2]); acc[1][3] = fmaf(a1, b.w, acc[1][3]);
      }
    }
    {
      float sr0 = sq[row0 + 2*ty + 0], sr1 = sq[row0 + 2*ty + 1];
#pragma unroll
      for (int c = 0; c < 4; ++c) {
        int gc = ct + (tx << 2) + c;
        float scv = sq[gc];
        float d20 = sr0 + scv - 2.0f * acc[0][c];
        float d21 = sr1 + scv - 2.0f * acc[1][c];
        float d0 = (d20 > 0.0f) ? sqrtf(fmaxf(d20, 1e-24f)) : 0.0f;
        float d1 = (d21 > 0.0f) ? sqrtf(fmaxf(d21, 1e-24f)) : 0.0f;
        if (gc == row0 + 2*ty + 0) d0 = INF;
        if (gc == row0 + 2*ty + 1) d1 = INF;
        Dtf[2*ty + 0][(tx << 2) + c] = d0;
        Dtf[2*ty + 1][(tx << 2) + c] = d1;
      }
    }
    __syncthreads();
    if (tid < RB) {
      float kth = topv[tid][KNN-1];
      for (int c = 0; c < CB; ++c) {
        float d = Dtf[tid][c];
        if (d < kth) {
          int gi = ct + c;
          int j = KNN - 1;
          while (j > 0 && topv[tid][j-1] > d) {
            topv[tid][j] = topv[tid][j-1]; topi[tid][j] = topi[tid][j-1]; --j;
          }
          topv[tid][j] = d; topi[tid][j] = gi;
          kth = topv[tid][KNN-1];
        }
      }
    }
    __syncthreads();
  }
  if (tid < RB) {
    int gr = row0 + tid;
#pragma unroll
    for (int j = 0; j < KNN; ++j) {
      outd[(size_t)gr * KNN + j] = topv[tid][j];
      outi[(size_t)gr * KNN + j] = topi[tid][j];
    }
  }
}

// ---------------------------------------------------------------- fused angular (ref pass + curr diff pass)
__global__ __launch_bounds__(256)
void k_ang2(const float* __restrict__ Ecur, const float* __restrict__ Eref,
            const int* __restrict__ knni, float* __restrict__ angpart)
{
  __shared__ float v[KNN][D];
  __shared__ float e[D];
  __shared__ float invn[KNN];
  __shared__ float cref[NPAIR];
  __shared__ float wpart[4];

  const int i = blockIdx.x;
  const int tid = threadIdx.x;
  const int lane = tid & 63;
  const int w = tid >> 6;

  float acc = 0.f;

#pragma unroll 1
  for (int pass = 0; pass < 2; ++pass) {
    const float* E = pass ? Ecur : Eref;
    const int* idx = knni + ((size_t)(pass ? 0 : 1) * N + i) * KNN;

    if (tid < 128)
      ((float4*)e)[tid] = ((const float4*)(E + (size_t)i * D))[tid];
    __syncthreads();

    for (int j = w; j < KNN; j += 4) {
      const float* src = E + (size_t)idx[j] * D;
      const int base = lane * 8;
      float4 x0 = *(const float4*)(src + base);
      float4 x1 = *(const float4*)(src + base + 4);
      float4 e0 = *(const float4*)(&e[base]);
      float4 e1 = *(const float4*)(&e[base + 4]);
      float d0 = x0.x-e0.x, d1 = x0.y-e0.y, d2 = x0.z-e0.z, d3 = x0.w-e0.w;
      float d4 = x1.x-e1.x, d5 = x1.y-e1.y, d6 = x1.z-e1.z, d7 = x1.w-e1.w;
      v[j][base+0]=d0; v[j][base+1]=d1; v[j][base+2]=d2; v[j][base+3]=d3;
      v[j][base+4]=d4; v[j][base+5]=d5; v[j][base+6]=d6; v[j][base+7]=d7;
      float s = d0*d0 + d1*d1 + d2*d2 + d3*d3 + d4*d4 + d5*d5 + d6*d6 + d7*d7;
#pragma unroll
      for (int o = 32; o; o >>= 1) s += __shfl_xor(s, o);
      if (lane == 0) invn[j] = 1.0f / fmaxf(sqrtf(s), 1e-12f);
    }
    __syncthreads();

    for (int p = w; p < NPAIR; p += 4) {
      int a = 0, q = p, rem = KNN - 1;
      while (q >= rem) { q -= rem; ++a; --rem; }
      int b = a + 1 + q;
      const float* va = v[a];
      const float* vb = v[b];
      const int base = lane * 8;
      float4 A0 = *(const float4*)(va + base);
      float4 A1 = *(const float4*)(va + base + 4);
      float4 B0 = *(const float4*)(vb + base);
      float4 B1 = *(const float4*)(vb + base + 4);
      float s = A0.x*B0.x + A0.y*B0.y + A0.z*B0.z + A0.w*B0.w
              + A1.x*B1.x + A1.y*B1.y + A1.z*B1.z + A1.w*B1.w;
#pragma unroll
      for (int o = 32; o; o >>= 1) s += __shfl_xor(s, o);
      if (lane == 0) {
        float cosv = s * invn[a] * invn[b];
        if (pass == 0) cref[p] = cosv;
        else { float dd = cosv - cref[p]; acc = fmaf(dd, dd, acc); }
      }
    }
    __syncthreads();
  }

  if (lane == 0) wpart[w] = acc;
  __syncthreads();
  if (tid == 0) angpart[i] = (wpart[0] + wpart[1]) + (wpart[2] + wpart[3]);
}

// ---------------------------------------------------------------- per-row stats
__global__ __launch_bounds__(256)
void k_stats(const float* __restrict__ knnd, float* __restrict__ dens,
             float* __restrict__ loss1part)
{
  __shared__ float red[256];
  int n = blockIdx.x * 256 + threadIdx.x;
  const float* dc = knnd + (size_t)n * KNN;
  const float* dr = knnd + (size_t)(N + n) * KNN;
  float mc = 0.f, mr = 0.f;
#pragma unroll
  for (int j = 0; j < KNN; ++j) { mc += dc[j]; mr += dr[j]; }
  mc *= (1.0f / KNN); mr *= (1.0f / KNN);
  float ic = 1.0f / (mc + EPSF);
  float ir = 1.0f / (mr + EPSF);
  float s = 0.f;
#pragma unroll
  for (int j = 0; j < KNN; ++j) {
    float t = dc[j] * ic - dr[j] * ir;
    s = fmaf(t, t, s);
  }
  dens[n] = ic;
  dens[N + n] = ir;
  red[threadIdx.x] = s;
  __syncthreads();
  for (int o = 128; o; o >>= 1) {
    if (threadIdx.x < o) red[threadIdx.x] += red[threadIdx.x + o];
    __syncthreads();
  }
  if (threadIdx.x == 0) loss1part[blockIdx.x] = red[0];
}

// ---------------------------------------------------------------- final combine
__global__ __launch_bounds__(256)
void k_final(const float* __restrict__ loss1part, const float* __restrict__ dens,
             const float* __restrict__ angpart, float* __restrict__ out)
{
  __shared__ float red[256];
  const int t = threadIdx.x;

  float sc = 0.f, sr = 0.f;
  for (int n = t; n < N; n += 256) { sc += dens[n]; sr += dens[N + n]; }
  red[t] = sc; __syncthreads();
  for (int o = 128; o; o >>= 1) { if (t < o) red[t] += red[t + o]; __syncthreads(); }
  float scm = red[0]; __syncthreads();
  red[t] = sr; __syncthreads();
  for (int o = 128; o; o >>= 1) { if (t < o) red[t] += red[t + o]; __syncthreads(); }
  float srm = red[0]; __syncthreads();

  float icm = 1.0f / (scm / (float)N + EPSF);
  float irm = 1.0f / (srm / (float)N + EPSF);

  float l2 = 0.f;
  for (int n = t; n < N; n += 256) {
    float dd = dens[n] * icm - dens[N + n] * irm;
    l2 = fmaf(dd, dd, l2);
  }
  red[t] = l2; __syncthreads();
  for (int o = 128; o; o >>= 1) { if (t < o) red[t] += red[t + o]; __syncthreads(); }
  float l2sum = red[0]; __syncthreads();

  float l1 = (t < 32) ? loss1part[t] : 0.f;
  red[t] = l1; __syncthreads();
  for (int o = 128; o; o >>= 1) { if (t < o) red[t] += red[t + o]; __syncthreads(); }
  float l1sum = red[0]; __syncthreads();

  float l3 = 0.f;
  for (int n = t; n < N; n += 256) l3 += angpart[n];
  red[t] = l3; __syncthreads();
  for (int o = 128; o; o >>= 1) { if (t < o) red[t] += red[t + o]; __syncthreads(); }
  float l3sum = red[0];

  if (t == 0) {
    out[0] = l1sum / (float)(N * KNN)
           + 0.5f * l2sum / (float)N
           + 0.5f * l3sum / (float)(N * NPAIR);
  }
}

// ---------------------------------------------------------------- launch
extern "C" void kernel_launch(void* const* d_in, const int* in_sizes, int n_in,
                              void* d_out, int out_size, void* d_ws, size_t ws_size,
                              hipStream_t stream)
{
  const float* emb = (const float*)d_in[0];
  const float* ref = (const float*)d_in[1];
  float* out = (float*)d_out;
  char* ws = (char*)d_ws;

  const size_t off_sq = 0;                                  // 2N f32
  const size_t off_hi = off_sq + (size_t)2 * N * 4;         // 2ND bf16
  const size_t off_lo = off_hi + (size_t)2 * N * D * 2;     // 2ND bf16

  const size_t m_off_pval = off_lo + (size_t)2 * N * D * 2;
  const size_t m_off_pidx = m_off_pval + (size_t)2 * 4 * N * KNN * 4;
  const size_t m_off_knnd = m_off_pidx + (size_t)2 * 4 * N * KNN * 4;
  const size_t m_off_knni = m_off_knnd + (size_t)2 * N * KNN * 4;
  const size_t m_off_angp = m_off_knni + (size_t)2 * N * KNN * 4;
  const size_t m_off_dens = m_off_angp + (size_t)N * 4;
  const size_t m_off_l1   = m_off_dens + (size_t)2 * N * 4;
  const size_t NEED_MED   = m_off_l1 + 4096;

  float* sq = (float*)(ws + off_sq);
  float* knnd; int* knni; float* angpart; float* dens; float* l1part;

  k_sqnorm<<<(2 * N) / 4, 256, 0, stream>>>(emb, ref, sq);

  if (ws_size >= NEED_MED) {
    unsigned short* hi = (unsigned short*)(ws + off_hi);
    unsigned short* lo = (unsigned short*)(ws + off_lo);
    float* pval = (float*)(ws + m_off_pval);
    int* pidx = (int*)(ws + m_off_pidx);
    knnd = (float*)(ws + m_off_knnd);
    knni = (int*)(ws + m_off_knni);
    angpart = (float*)(ws + m_off_angp);
    dens = (float*)(ws + m_off_dens);
    l1part = (float*)(ws + m_off_l1);

    k_split<<<(2 * N * D / 8) / 256, 256, 0, stream>>>(emb, ref, hi, lo);
    k_knn8<<<dim3(N / 256, 4, 2), 512, 0, stream>>>(hi, lo, sq, pval, pidx);
    k_merge<<<(2 * N) / 256, 256, 0, stream>>>(pval, pidx, knnd, knni);
  } else {
    size_t o = off_hi;
    knnd = (float*)(ws + o); o += (size_t)2 * N * KNN * 4;
    knni = (int*)(ws + o);   o += (size_t)2 * N * KNN * 4;
    angpart = (float*)(ws + o); o += (size_t)N * 4;
    dens = (float*)(ws + o); o += (size_t)2 * N * 4;
    l1part = (float*)(ws + o);
    k_knn_fb<<<dim3(N / RB, 2), 256, 0, stream>>>(emb, ref, sq, knnd, knni);
  }

  k_ang2<<<N, 256, 0, stream>>>(emb, ref, knni, angpart);
  k_stats<<<N / 256, 256, 0, stream>>>(knnd, dens, l1part);
  k_final<<<1, 256, 0, stream>>>(l1part, dens, angpart, out);
}

// Round 8
// 977.981 us; speedup vs baseline: 1.3745x; 1.3745x over previous
//
#include <hip/hip_runtime.h>

#define N 8192
#define D 512
#define KNN 15
#define NC 20      // per-split candidate list
#define NCAND 32   // rescored candidates per row
#define NPAIR 105
#define EPSF 1e-8f

#define RB 32
#define CB 64
#define KB 32

#define INF __int_as_float(0x7f800000)

typedef __attribute__((ext_vector_type(4))) float f32x4;
typedef __attribute__((ext_vector_type(8))) short s16x8;
typedef __attribute__((ext_vector_type(8))) unsigned short u16x8;
typedef unsigned long long u64;

typedef const unsigned int __attribute__((address_space(1)))* gp_t;
typedef unsigned int __attribute__((address_space(3)))* lp_t;

__device__ __forceinline__ void gl_lds16(const void* g, void* l) {
  __builtin_amdgcn_global_load_lds((gp_t)g, (lp_t)l, 16, 0, 0);
}

__device__ __forceinline__ unsigned short bf16_rne(float x) {
  unsigned int u = __float_as_uint(x);
  return (unsigned short)((u + 0x7fffu + ((u >> 16) & 1u)) >> 16);
}

#define VMCNT4 asm volatile("s_waitcnt vmcnt(4)" ::: "memory")
#define VMCNT0 asm volatile("s_waitcnt vmcnt(0)" ::: "memory")
#define LGKM0  asm volatile("s_waitcnt lgkmcnt(0)" ::: "memory")
#define CFENCE asm volatile("" ::: "memory")

// ---------------------------------------------------------------- sq norms
__global__ __launch_bounds__(256)
void k_sqnorm(const float* __restrict__ A, const float* __restrict__ B,
              float* __restrict__ sq)
{
  int tid = threadIdx.x;
  int lane = tid & 63;
  int row = blockIdx.x * 4 + (tid >> 6);          // 0 .. 2N-1
  const float* src = (row < N) ? (A + (size_t)row * D)
                               : (B + (size_t)(row - N) * D);
  const float4* s4 = (const float4*)src + lane * 2;
  float4 x0 = s4[0], x1 = s4[1];
  float s = x0.x*x0.x + x0.y*x0.y + x0.z*x0.z + x0.w*x0.w
          + x1.x*x1.x + x1.y*x1.y + x1.z*x1.z + x1.w*x1.w;
#pragma unroll
  for (int o = 32; o; o >>= 1) s += __shfl_xor(s, o);
  if (lane == 0) sq[row] = s;
}

// ---------------------------------------------------------------- bf16 hi split (no lo)
__global__ __launch_bounds__(256)
void k_split_hi(const float* __restrict__ A, const float* __restrict__ B,
                unsigned short* __restrict__ hi)
{
  size_t t = (size_t)blockIdx.x * 256 + threadIdx.x;
  size_t base = t * 8;
  const float* src = (base < (size_t)N * D) ? (A + base) : (B + (base - (size_t)N * D));
  float4 x0 = ((const float4*)src)[0];
  float4 x1 = ((const float4*)src)[1];
  float xs[8] = {x0.x, x0.y, x0.z, x0.w, x1.x, x1.y, x1.z, x1.w};
  u16x8 hv;
#pragma unroll
  for (int j = 0; j < 8; ++j) hv[j] = bf16_rne(xs[j]);
  *(u16x8*)(hi + base) = hv;
}

// ================================================================ stage 1:
// approx (hi-only) MFMA gram + per-split top-20 candidates.
// R5 k_med skeleton; staging halved (no lo). LDS 40960 B:
//   stage dbuf 2 x 16KB at [0,32768): per buf Ahi[0,8K) Bhi[8K,16K),
//   128 rows x 64B each. Epilogue overlays Dt[128][65] f32;
//   merge overlays SV[128][40] f32 + SI[128][40] i32.
__global__ __launch_bounds__(256, 2)
void k_knn1(const unsigned short* __restrict__ hi,
            const float* __restrict__ sqall,
            float* __restrict__ pval, int* __restrict__ pidx)
{
  __shared__ __align__(16) char smem[40960];
  float* Dt = (float*)smem;
  float* SV = (float*)smem;
  int*   SI = (int*)(smem + 20480);

  const int tid = threadIdx.x;
  const int lane = tid & 63, w = tid >> 6;
  const int wr = w >> 1, wc = w & 1;
  const int fr = lane & 15, fq = lane >> 4;
  const int sgx = fq ^ ((fr >> 1) & 3);     // read-side seg swizzle

  const int rb = blockIdx.x, split = blockIdx.y, which = blockIdx.z;
  const int row0 = rb * 128;
  const int c0 = split * 2048;
  const unsigned short* Hi = hi + (size_t)which * N * D;
  const float* sq = sqall + which * N;

  // staging: thread -> (row rr, seg); source seg pre-swizzled, LDS linear
  const int rr = tid >> 2, sseg = tid & 3;
  const int ssg = sseg ^ ((rr >> 1) & 3);
  const unsigned short* pAh = Hi + (size_t)(row0 + rr) * D + ssg * 8;
  const unsigned short* pBh = Hi + (size_t)(c0 + rr) * D + ssg * 8;

  auto stage = [&](int sel) {
    char* d = smem + (sel << 14) + (w << 10);   // wave-uniform dest base
    gl_lds16(pAh, d);
    gl_lds16(pAh + 32768, d + 4096);            // rows +64 (+65536 B global)
    gl_lds16(pBh, d + 8192);
    gl_lds16(pBh + 32768, d + 12288);
    pAh += 32; pBh += 32;                        // next K-step
  };

  const int srow = tid >> 1, ssub = tid & 1;
  float tv[NC]; int ti[NC];
#pragma unroll
  for (int j = 0; j < NC; ++j) { tv[j] = INF; ti[j] = -1; }

  float sqr[4][4];
#pragma unroll
  for (int m = 0; m < 4; ++m)
#pragma unroll
    for (int j = 0; j < 4; ++j)
      sqr[m][j] = sq[row0 + wr * 64 + m * 16 + fq * 4 + j];

#pragma unroll 1
  for (int t = 0; t < 16; ++t) {
    const int ct = c0 + t * 128;
    float sqc[4];
#pragma unroll
    for (int n = 0; n < 4; ++n) sqc[n] = sq[ct + wc * 64 + n * 16 + fr];

    f32x4 acc[4][4];
#pragma unroll
    for (int m = 0; m < 4; ++m)
#pragma unroll
      for (int n = 0; n < 4; ++n) acc[m][n] = (f32x4){0.f, 0.f, 0.f, 0.f};

    stage(0);
    int cur = 0;
#pragma unroll 1
    for (int kt = 0; kt < 16; ++kt) {
      if (kt < 15) {
        stage(cur ^ 1);   // 8 outstanding
        VMCNT4;           // own 4 oldest = buf[cur] loads complete
      } else {
        VMCNT0;
      }
      __builtin_amdgcn_s_barrier();
      CFENCE;

      const short* Sb = (const short*)(smem + (cur << 14));
      s16x8 ah[4], bh[4];
#pragma unroll
      for (int m = 0; m < 4; ++m)
        ah[m] = *(const s16x8*)(Sb + (wr * 64 + m * 16 + fr) * 32 + sgx * 8);
#pragma unroll
      for (int n = 0; n < 4; ++n)
        bh[n] = *(const s16x8*)(Sb + 4096 + (wc * 64 + n * 16 + fr) * 32 + sgx * 8);
#pragma unroll
      for (int m = 0; m < 4; ++m)
#pragma unroll
        for (int n = 0; n < 4; ++n)
          acc[m][n] = __builtin_amdgcn_mfma_f32_16x16x32_bf16(ah[m], bh[n], acc[m][n], 0, 0, 0);

      LGKM0;
      __builtin_amdgcn_s_barrier();
      CFENCE;
      cur ^= 1;
    }
    pAh -= 512; pBh += 65024;

    // ---- epilogue: approx distances + per-row top-20 scan
#pragma unroll 1
    for (int h = 0; h < 2; ++h) {
      if (wc == h) {
#pragma unroll
        for (int m = 0; m < 4; ++m)
#pragma unroll
          for (int n = 0; n < 4; ++n) {
            const int cl = n * 16 + fr;
            const int gcol = ct + h * 64 + cl;
            const int rbase = wr * 64 + m * 16 + fq * 4;
#pragma unroll
            for (int j = 0; j < 4; ++j) {
              float d2 = fmaf(-2.0f, acc[m][n][j], sqr[m][j] + sqc[n]);
              if (row0 + rbase + j == gcol) d2 = INF;   // exclude self
              Dt[(rbase + j) * 65 + cl] = d2;
            }
          }
      }
      __syncthreads();
      {
        const int cb2 = ssub * 32;
        float kth = tv[NC - 1];
#pragma unroll 1
        for (int c = 0; c < 32; ++c) {
          const float d2 = Dt[srow * 65 + cb2 + c];
          if (d2 < kth) {
            const int gi = ct + h * 64 + cb2 + c;
#pragma unroll
            for (int j = NC - 1; j >= 1; --j) {
              const bool ja = (tv[j] > d2), jb = (tv[j - 1] > d2);
              const float nv = jb ? tv[j - 1] : (ja ? d2 : tv[j]);
              const int ni = jb ? ti[j - 1] : (ja ? gi : ti[j]);
              tv[j] = nv; ti[j] = ni;
            }
            if (tv[0] > d2) { tv[0] = d2; ti[0] = gi; }
            kth = tv[NC - 1];
          }
        }
      }
      __syncthreads();
    }
  }

  // ---- block end: merge 2 scanner lists per row -> per-split top-20 (raw d2)
#pragma unroll
  for (int j = 0; j < NC; ++j) {
    SV[srow * 40 + ssub * 20 + j] = tv[j];
    SI[srow * 40 + ssub * 20 + j] = ti[j];
  }
  __syncthreads();
  if (tid < 128) {
    const int grow = row0 + tid;
    const size_t pb = (((size_t)which * 4 + split) * N + grow) * NC;
    int p0 = 0, p1 = 0;
#pragma unroll
    for (int j = 0; j < NC; ++j) {
      const float v0 = (p0 < NC) ? SV[tid * 40 + p0] : INF;
      const float v1 = (p1 < NC) ? SV[tid * 40 + 20 + p1] : INF;
      const int i0 = (p0 < NC) ? SI[tid * 40 + p0] : 0x7fffffff;
      const int i1 = (p1 < NC) ? SI[tid * 40 + 20 + p1] : 0x7fffffff;
      const bool t0 = (v0 < v1) || (v0 == v1 && i0 < i1);
      pval[pb + j] = t0 ? v0 : v1;
      pidx[pb + j] = t0 ? i0 : i1;
      if (t0) ++p0; else ++p1;
    }
  }
}

// ---------------------------------------------------------------- merge 4 splits -> top-32 candidate indices
__global__ __launch_bounds__(256)
void k_cand(const float* __restrict__ pval, const int* __restrict__ pidx,
            int* __restrict__ cidx)
{
  const int flat = blockIdx.x * 256 + threadIdx.x;   // 0..16383
  const int which = flat >> 13, row = flat & (N - 1);
  const size_t b0 = (((size_t)which * 4 + 0) * N + row) * NC;
  const size_t b1 = (((size_t)which * 4 + 1) * N + row) * NC;
  const size_t b2 = (((size_t)which * 4 + 2) * N + row) * NC;
  const size_t b3 = (((size_t)which * 4 + 3) * N + row) * NC;
  float v0 = pval[b0], v1 = pval[b1], v2 = pval[b2], v3 = pval[b3];
  int i0 = pidx[b0], i1 = pidx[b1], i2 = pidx[b2], i3 = pidx[b3];
  int p0 = 0, p1 = 0, p2 = 0, p3 = 0;
  const size_t ob = ((size_t)which * N + row) * NCAND;
#pragma unroll 1
  for (int j = 0; j < NCAND; ++j) {
    const bool a01 = (v0 < v1) || (v0 == v1 && i0 < i1);
    const float va = a01 ? v0 : v1; const int ia = a01 ? i0 : i1;
    const bool a23 = (v2 < v3) || (v2 == v3 && i2 < i3);
    const float vb = a23 ? v2 : v3; const int ib = a23 ? i2 : i3;
    const bool ab = (va < vb) || (va == vb && ia < ib);
    cidx[ob + j] = ab ? ia : ib;
    if (ab) {
      if (a01) { ++p0; v0 = (p0 < NC) ? pval[b0 + p0] : INF; i0 = (p0 < NC) ? pidx[b0 + p0] : 0x7fffffff; }
      else     { ++p1; v1 = (p1 < NC) ? pval[b1 + p1] : INF; i1 = (p1 < NC) ? pidx[b1 + p1] : 0x7fffffff; }
    } else {
      if (a23) { ++p2; v2 = (p2 < NC) ? pval[b2 + p2] : INF; i2 = (p2 < NC) ? pidx[b2 + p2] : 0x7fffffff; }
      else     { ++p3; v3 = (p3 < NC) ? pval[b3 + p3] : INF; i3 = (p3 < NC) ? pidx[b3 + p3] : 0x7fffffff; }
    }
  }
}

// ---------------------------------------------------------------- exact f32 rescore of 32 candidates -> top-15
__global__ __launch_bounds__(256)
void k_rescore(const float* __restrict__ emb, const float* __restrict__ ref,
               const float* __restrict__ sqall, const int* __restrict__ cidx,
               float* __restrict__ knnd, int* __restrict__ knni)
{
  const int tid = threadIdx.x;
  const int lane = tid & 63, w = tid >> 6;
  const int flat = blockIdx.x * 4 + w;     // 0..16383
  const int which = flat >> 13, row = flat & (N - 1);
  const float* E = which ? ref : emb;
  const float* sq = sqall + which * N;
  const int* cb = cidx + ((size_t)which * N + row) * NCAND;

  // own row: 8 f32 per lane
  const float4* orow = (const float4*)(E + (size_t)row * D) + lane * 2;
  const float4 o0 = orow[0], o1 = orow[1];
  const float sqr = sq[row];

  u64 mykey = ~0ull;
#pragma unroll 1
  for (int c = 0; c < NCAND; ++c) {
    const int cl = cb[c];                          // uniform -> broadcast
    const float4* crow = (const float4*)(E + (size_t)cl * D) + lane * 2;
    const float4 c0 = crow[0], c1 = crow[1];
    float s = o0.x*c0.x + o0.y*c0.y + o0.z*c0.z + o0.w*c0.w
            + o1.x*c1.x + o1.y*c1.y + o1.z*c1.z + o1.w*c1.w;
#pragma unroll
    for (int o = 32; o; o >>= 1) s += __shfl_xor(s, o);
    float d2 = fmaf(-2.0f, s, sqr + sq[cl]);
    d2 = fmaxf(d2, 0.0f);                          // key-safe (sign bit)
    const u64 key = ((u64)__float_as_uint(d2) << 32) | (unsigned)cl;
    if (lane == c) mykey = key;
  }

  const size_t ob = ((size_t)which * N + row) * KNN;
#pragma unroll 1
  for (int r = 0; r < KNN; ++r) {
    u64 m = mykey;
#pragma unroll
    for (int o = 32; o; o >>= 1) {
      const u64 t2 = __shfl_xor(m, o);
      if (t2 < m) m = t2;
    }
    if (mykey == m) mykey = ~0ull;                 // unique (idx distinct)
    if (lane == 0) {
      const float d2v = __uint_as_float((unsigned)(m >> 32));
      knnd[ob + r] = (d2v > 0.f) ? sqrtf(fmaxf(d2v, 1e-24f)) : 0.f;
      knni[ob + r] = (int)(m & 0xffffffffu);
    }
  }
}

// ---------------------------------------------------------------- fallback: f32 VALU gram KNN
__global__ __launch_bounds__(256)
void k_knn_fb(const float* __restrict__ Ecur, const float* __restrict__ Eref,
              const float* __restrict__ sqall,
              float* __restrict__ knnd, int* __restrict__ knni)
{
  const int which = blockIdx.y;
  const float* E = which ? Eref : Ecur;
  const float* sq = sqall + which * N;
  float* outd = knnd + (size_t)which * N * KNN;
  int* outi = knni + (size_t)which * N * KNN;
  const int row0 = blockIdx.x * RB;

  __shared__ float As[RB][KB + 1];
  __shared__ float Bs[KB][CB + 4];
  __shared__ float Dtf[RB][CB + 1];
  __shared__ float topv[RB][KNN];
  __shared__ int topi[RB][KNN];

  const int tid = threadIdx.x;
  const int tx = tid & 15, ty = tid >> 4;

  if (tid < RB) {
#pragma unroll
    for (int j = 0; j < KNN; ++j) { topv[tid][j] = INF; topi[tid][j] = -1; }
  }

  for (int ct = 0; ct < N; ct += CB) {
    float acc[2][4] = {{0.f,0.f,0.f,0.f},{0.f,0.f,0.f,0.f}};
    for (int kt = 0; kt < D; kt += KB) {
      __syncthreads();
      {
        int r = tid >> 3, c4 = (tid & 7) << 2;
        const float4 v = *(const float4*)&E[(size_t)(row0 + r) * D + kt + c4];
        As[r][c4+0] = v.x; As[r][c4+1] = v.y; As[r][c4+2] = v.z; As[r][c4+3] = v.w;
      }
      {
        int k = tid & 31, cbase = tid >> 5;
#pragma unroll
        for (int i = 0; i < 8; ++i) {
          int c = cbase + (i << 3);
          Bs[k][c] = E[(size_t)(ct + c) * D + kt + k];
        }
      }
      __syncthreads();
#pragma unroll
      for (int k = 0; k < KB; ++k) {
        float a0 = As[2*ty + 0][k], a1 = As[2*ty + 1][k];
        float4 b = *(const float4*)&Bs[k][tx << 2];
        acc[0][0] = fmaf(a0, b.x, acc[0][0]); acc[0][1] = fmaf(a0, b.y, acc[0][1]);
        acc[0][2] = fmaf(a0, b.z, acc[0][2]); acc[0][3] = fmaf(a0, b.w, acc[0][3]);
        acc[1][0] = fmaf(a1, b.x, acc[1][0]); acc[1][1] = fmaf(a1, b.y, acc[1][1]);
        acc[1][2] = fmaf(a1, b.z, acc[1][2]); acc[1][3] = fmaf(a1, b.w, acc[1][3]);
      }
    }
    {
      float sr0 = sq[row0 + 2*ty + 0], sr1 = sq[row0 + 2*ty + 1];
#pragma unroll
      for (int c = 0; c < 4; ++c) {
        int gc = ct + (tx << 2) + c;
        float scv = sq[gc];
        float d20 = sr0 + scv - 2.0f * acc[0][c];
        float d21 = sr1 + scv - 2.0f * acc[1][c];
        float d0 = (d20 > 0.0f) ? sqrtf(fmaxf(d20, 1e-24f)) : 0.0f;
        float d1 = (d21 > 0.0f) ? sqrtf(fmaxf(d21, 1e-24f)) : 0.0f;
        if (gc == row0 + 2*ty + 0) d0 = INF;
        if (gc == row0 + 2*ty + 1) d1 = INF;
        Dtf[2*ty + 0][(tx << 2) + c] = d0;
        Dtf[2*ty + 1][(tx << 2) + c] = d1;
      }
    }
    __syncthreads();
    if (tid < RB) {
      float kth = topv[tid][KNN-1];
      for (int c = 0; c < CB; ++c) {
        float d = Dtf[tid][c];
        if (d < kth) {
          int gi = ct + c;
          int j = KNN - 1;
          while (j > 0 && topv[tid][j-1] > d) {
            topv[tid][j] = topv[tid][j-1]; topi[tid][j] = topi[tid][j-1]; --j;
          }
          topv[tid][j] = d; topi[tid][j] = gi;
          kth = topv[tid][KNN-1];
        }
      }
    }
    __syncthreads();
  }
  if (tid < RB) {
    int gr = row0 + tid;
#pragma unroll
    for (int j = 0; j < KNN; ++j) {
      outd[(size_t)gr * KNN + j] = topv[tid][j];
      outi[(size_t)gr * KNN + j] = topi[tid][j];
    }
  }
}

// ---------------------------------------------------------------- fused angular (ref pass + curr diff pass)
__global__ __launch_bounds__(256)
void k_ang2(const float* __restrict__ Ecur, const float* __restrict__ Eref,
            const int* __restrict__ knni, float* __restrict__ angpart)
{
  __shared__ float v[KNN][D];
  __shared__ float e[D];
  __shared__ float invn[KNN];
  __shared__ float cref[NPAIR];
  __shared__ float wpart[4];

  const int i = blockIdx.x;
  const int tid = threadIdx.x;
  const int lane = tid & 63;
  const int w = tid >> 6;

  float acc = 0.f;

#pragma unroll 1
  for (int pass = 0; pass < 2; ++pass) {
    const float* E = pass ? Ecur : Eref;
    const int* idx = knni + ((size_t)(pass ? 0 : 1) * N + i) * KNN;

    if (tid < 128)
      ((float4*)e)[tid] = ((const float4*)(E + (size_t)i * D))[tid];
    __syncthreads();

    for (int j = w; j < KNN; j += 4) {
      const float* src = E + (size_t)idx[j] * D;
      const int base = lane * 8;
      float4 x0 = *(const float4*)(src + base);
      float4 x1 = *(const float4*)(src + base + 4);
      float4 e0 = *(const float4*)(&e[base]);
      float4 e1 = *(const float4*)(&e[base + 4]);
      float d0 = x0.x-e0.x, d1 = x0.y-e0.y, d2 = x0.z-e0.z, d3 = x0.w-e0.w;
      float d4 = x1.x-e1.x, d5 = x1.y-e1.y, d6 = x1.z-e1.z, d7 = x1.w-e1.w;
      v[j][base+0]=d0; v[j][base+1]=d1; v[j][base+2]=d2; v[j][base+3]=d3;
      v[j][base+4]=d4; v[j][base+5]=d5; v[j][base+6]=d6; v[j][base+7]=d7;
      float s = d0*d0 + d1*d1 + d2*d2 + d3*d3 + d4*d4 + d5*d5 + d6*d6 + d7*d7;
#pragma unroll
      for (int o = 32; o; o >>= 1) s += __shfl_xor(s, o);
      if (lane == 0) invn[j] = 1.0f / fmaxf(sqrtf(s), 1e-12f);
    }
    __syncthreads();

    for (int p = w; p < NPAIR; p += 4) {
      int a = 0, q = p, rem = KNN - 1;
      while (q >= rem) { q -= rem; ++a; --rem; }
      int b = a + 1 + q;
      const float* va = v[a];
      const float* vb = v[b];
      const int base = lane * 8;
      float4 A0 = *(const float4*)(va + base);
      float4 A1 = *(const float4*)(va + base + 4);
      float4 B0 = *(const float4*)(vb + base);
      float4 B1 = *(const float4*)(vb + base + 4);
      float s = A0.x*B0.x + A0.y*B0.y + A0.z*B0.z + A0.w*B0.w
              + A1.x*B1.x + A1.y*B1.y + A1.z*B1.z + A1.w*B1.w;
#pragma unroll
      for (int o = 32; o; o >>= 1) s += __shfl_xor(s, o);
      if (lane == 0) {
        float cosv = s * invn[a] * invn[b];
        if (pass == 0) cref[p] = cosv;
        else { float dd = cosv - cref[p]; acc = fmaf(dd, dd, acc); }
      }
    }
    __syncthreads();
  }

  if (lane == 0) wpart[w] = acc;
  __syncthreads();
  if (tid == 0) angpart[i] = (wpart[0] + wpart[1]) + (wpart[2] + wpart[3]);
}

// ---------------------------------------------------------------- per-row stats
__global__ __launch_bounds__(256)
void k_stats(const float* __restrict__ knnd, float* __restrict__ dens,
             float* __restrict__ loss1part)
{
  __shared__ float red[256];
  int n = blockIdx.x * 256 + threadIdx.x;
  const float* dc = knnd + (size_t)n * KNN;
  const float* dr = knnd + (size_t)(N + n) * KNN;
  float mc = 0.f, mr = 0.f;
#pragma unroll
  for (int j = 0; j < KNN; ++j) { mc += dc[j]; mr += dr[j]; }
  mc *= (1.0f / KNN); mr *= (1.0f / KNN);
  float ic = 1.0f / (mc + EPSF);
  float ir = 1.0f / (mr + EPSF);
  float s = 0.f;
#pragma unroll
  for (int j = 0; j < KNN; ++j) {
    float t = dc[j] * ic - dr[j] * ir;
    s = fmaf(t, t, s);
  }
  dens[n] = ic;
  dens[N + n] = ir;
  red[threadIdx.x] = s;
  __syncthreads();
  for (int o = 128; o; o >>= 1) {
    if (threadIdx.x < o) red[threadIdx.x] += red[threadIdx.x + o];
    __syncthreads();
  }
  if (threadIdx.x == 0) loss1part[blockIdx.x] = red[0];
}

// ---------------------------------------------------------------- final combine
__global__ __launch_bounds__(256)
void k_final(const float* __restrict__ loss1part, const float* __restrict__ dens,
             const float* __restrict__ angpart, float* __restrict__ out)
{
  __shared__ float red[256];
  const int t = threadIdx.x;

  float sc = 0.f, sr = 0.f;
  for (int n = t; n < N; n += 256) { sc += dens[n]; sr += dens[N + n]; }
  red[t] = sc; __syncthreads();
  for (int o = 128; o; o >>= 1) { if (t < o) red[t] += red[t + o]; __syncthreads(); }
  float scm = red[0]; __syncthreads();
  red[t] = sr; __syncthreads();
  for (int o = 128; o; o >>= 1) { if (t < o) red[t] += red[t + o]; __syncthreads(); }
  float srm = red[0]; __syncthreads();

  float icm = 1.0f / (scm / (float)N + EPSF);
  float irm = 1.0f / (srm / (float)N + EPSF);

  float l2 = 0.f;
  for (int n = t; n < N; n += 256) {
    float dd = dens[n] * icm - dens[N + n] * irm;
    l2 = fmaf(dd, dd, l2);
  }
  red[t] = l2; __syncthreads();
  for (int o = 128; o; o >>= 1) { if (t < o) red[t] += red[t + o]; __syncthreads(); }
  float l2sum = red[0]; __syncthreads();

  float l1 = (t < 32) ? loss1part[t] : 0.f;
  red[t] = l1; __syncthreads();
  for (int o = 128; o; o >>= 1) { if (t < o) red[t] += red[t + o]; __syncthreads(); }
  float l1sum = red[0]; __syncthreads();

  float l3 = 0.f;
  for (int n = t; n < N; n += 256) l3 += angpart[n];
  red[t] = l3; __syncthreads();
  for (int o = 128; o; o >>= 1) { if (t < o) red[t] += red[t + o]; __syncthreads(); }
  float l3sum = red[0];

  if (t == 0) {
    out[0] = l1sum / (float)(N * KNN)
           + 0.5f * l2sum / (float)N
           + 0.5f * l3sum / (float)(N * NPAIR);
  }
}

// ---------------------------------------------------------------- launch
extern "C" void kernel_launch(void* const* d_in, const int* in_sizes, int n_in,
                              void* d_out, int out_size, void* d_ws, size_t ws_size,
                              hipStream_t stream)
{
  const float* emb = (const float*)d_in[0];
  const float* ref = (const float*)d_in[1];
  float* out = (float*)d_out;
  char* ws = (char*)d_ws;

  const size_t off_sq = 0;                                  // 2N f32
  const size_t off_hi = off_sq + (size_t)2 * N * 4;         // 2ND bf16 (hi only)

  const size_t m_off_pval = off_hi + (size_t)2 * N * D * 2;              // 2*4*N*20 f32
  const size_t m_off_pidx = m_off_pval + (size_t)2 * 4 * N * NC * 4;     // 2*4*N*20 i32
  const size_t m_off_cidx = m_off_pidx + (size_t)2 * 4 * N * NC * 4;     // 2*N*32 i32
  const size_t m_off_knnd = m_off_cidx + (size_t)2 * N * NCAND * 4;
  const size_t m_off_knni = m_off_knnd + (size_t)2 * N * KNN * 4;
  const size_t m_off_angp = m_off_knni + (size_t)2 * N * KNN * 4;
  const size_t m_off_dens = m_off_angp + (size_t)N * 4;
  const size_t m_off_l1   = m_off_dens + (size_t)2 * N * 4;
  const size_t NEED       = m_off_l1 + 4096;

  float* sq = (float*)(ws + off_sq);
  float* knnd; int* knni; float* angpart; float* dens; float* l1part;

  k_sqnorm<<<(2 * N) / 4, 256, 0, stream>>>(emb, ref, sq);

  if (ws_size >= NEED) {
    unsigned short* hi = (unsigned short*)(ws + off_hi);
    float* pval = (float*)(ws + m_off_pval);
    int* pidx = (int*)(ws + m_off_pidx);
    int* cidx = (int*)(ws + m_off_cidx);
    knnd = (float*)(ws + m_off_knnd);
    knni = (int*)(ws + m_off_knni);
    angpart = (float*)(ws + m_off_angp);
    dens = (float*)(ws + m_off_dens);
    l1part = (float*)(ws + m_off_l1);

    k_split_hi<<<(2 * N * D / 8) / 256, 256, 0, stream>>>(emb, ref, hi);
    k_knn1<<<dim3(N / 128, 4, 2), 256, 0, stream>>>(hi, sq, pval, pidx);
    k_cand<<<(2 * N) / 256, 256, 0, stream>>>(pval, pidx, cidx);
    k_rescore<<<(2 * N) / 4, 256, 0, stream>>>(emb, ref, sq, cidx, knnd, knni);
  } else {
    size_t o = off_hi;
    knnd = (float*)(ws + o); o += (size_t)2 * N * KNN * 4;
    knni = (int*)(ws + o);   o += (size_t)2 * N * KNN * 4;
    angpart = (float*)(ws + o); o += (size_t)N * 4;
    dens = (float*)(ws + o); o += (size_t)2 * N * 4;
    l1part = (float*)(ws + o);
    k_knn_fb<<<dim3(N / RB, 2), 256, 0, stream>>>(emb, ref, sq, knnd, knni);
  }

  k_ang2<<<N, 256, 0, stream>>>(emb, ref, knni, angpart);
  k_stats<<<N / 256, 256, 0, stream>>>(knnd, dens, l1part);
  k_final<<<1, 256, 0, stream>>>(l1part, dens, angpart, out);
}

// Round 9
// 821.577 us; speedup vs baseline: 1.6362x; 1.1904x over previous
//
#include <hip/hip_runtime.h>

#define N 8192
#define D 512
#define KNN 15
#define SC 8       // per-scanner register list
#define NC 16      // per-split candidate list (2 scanners merged)
#define NCAND 32   // rescored candidates per row
#define NPAIR 105
#define EPSF 1e-8f

#define RB 32
#define CB 64
#define KB 32

#define INF __int_as_float(0x7f800000)

typedef __attribute__((ext_vector_type(4))) float f32x4;
typedef __attribute__((ext_vector_type(8))) short s16x8;
typedef __attribute__((ext_vector_type(8))) unsigned short u16x8;
typedef unsigned long long u64;

typedef const unsigned int __attribute__((address_space(1)))* gp_t;
typedef unsigned int __attribute__((address_space(3)))* lp_t;

__device__ __forceinline__ void gl_lds16(const void* g, void* l) {
  __builtin_amdgcn_global_load_lds((gp_t)g, (lp_t)l, 16, 0, 0);
}

__device__ __forceinline__ unsigned short bf16_rne(float x) {
  unsigned int u = __float_as_uint(x);
  return (unsigned short)((u + 0x7fffu + ((u >> 16) & 1u)) >> 16);
}

#define VMCNT4 asm volatile("s_waitcnt vmcnt(4)" ::: "memory")
#define VMCNT0 asm volatile("s_waitcnt vmcnt(0)" ::: "memory")
#define LGKM0  asm volatile("s_waitcnt lgkmcnt(0)" ::: "memory")
#define CFENCE asm volatile("" ::: "memory")

// ---------------------------------------------------------------- sq norms
__global__ __launch_bounds__(256)
void k_sqnorm(const float* __restrict__ A, const float* __restrict__ B,
              float* __restrict__ sq)
{
  int tid = threadIdx.x;
  int lane = tid & 63;
  int row = blockIdx.x * 4 + (tid >> 6);          // 0 .. 2N-1
  const float* src = (row < N) ? (A + (size_t)row * D)
                               : (B + (size_t)(row - N) * D);
  const float4* s4 = (const float4*)src + lane * 2;
  float4 x0 = s4[0], x1 = s4[1];
  float s = x0.x*x0.x + x0.y*x0.y + x0.z*x0.z + x0.w*x0.w
          + x1.x*x1.x + x1.y*x1.y + x1.z*x1.z + x1.w*x1.w;
#pragma unroll
  for (int o = 32; o; o >>= 1) s += __shfl_xor(s, o);
  if (lane == 0) sq[row] = s;
}

// ---------------------------------------------------------------- bf16 hi split (no lo)
__global__ __launch_bounds__(256)
void k_split_hi(const float* __restrict__ A, const float* __restrict__ B,
                unsigned short* __restrict__ hi)
{
  size_t t = (size_t)blockIdx.x * 256 + threadIdx.x;
  size_t base = t * 8;
  const float* src = (base < (size_t)N * D) ? (A + base) : (B + (base - (size_t)N * D));
  float4 x0 = ((const float4*)src)[0];
  float4 x1 = ((const float4*)src)[1];
  float xs[8] = {x0.x, x0.y, x0.z, x0.w, x1.x, x1.y, x1.z, x1.w};
  u16x8 hv;
#pragma unroll
  for (int j = 0; j < 8; ++j) hv[j] = bf16_rne(xs[j]);
  *(u16x8*)(hi + base) = hv;
}

// ================================================================ stage 1:
// approx (hi-only) MFMA gram + per-split top-16 candidates.
// LDS 40960 B: stage dbuf 2 x 16KB at [0,32768); epilogue overlays
// Dt[128][68] f32 (34816 B); merge overlays SV[128][16] f32 + SI[128][16] i32.
__global__ __launch_bounds__(256, 2)
void k_knn1(const unsigned short* __restrict__ hi,
            const float* __restrict__ sqall,
            float* __restrict__ pval, int* __restrict__ pidx)
{
  __shared__ __align__(16) char smem[40960];
  float* Dt = (float*)smem;                 // [128][68]
  float* SV = (float*)smem;                 // [128][16]
  int*   SI = (int*)(smem + 8192);          // [128][16]

  const int tid = threadIdx.x;
  const int lane = tid & 63, w = tid >> 6;
  const int wr = w >> 1, wc = w & 1;
  const int fr = lane & 15, fq = lane >> 4;
  const int sgx = fq ^ ((fr >> 1) & 3);     // read-side seg swizzle

  const int rb = blockIdx.x, split = blockIdx.y, which = blockIdx.z;
  const int row0 = rb * 128;
  const int c0 = split * 2048;
  const unsigned short* Hi = hi + (size_t)which * N * D;
  const float* sq = sqall + which * N;

  // staging: thread -> (row rr, seg); source seg pre-swizzled, LDS linear
  const int rr = tid >> 2, sseg = tid & 3;
  const int ssg = sseg ^ ((rr >> 1) & 3);
  const unsigned short* pAh = Hi + (size_t)(row0 + rr) * D + ssg * 8;
  const unsigned short* pBh = Hi + (size_t)(c0 + rr) * D + ssg * 8;

  auto stage = [&](int sel) {
    char* d = smem + (sel << 14) + (w << 10);   // wave-uniform dest base
    gl_lds16(pAh, d);
    gl_lds16(pAh + 32768, d + 4096);            // rows +64 (+65536 B global)
    gl_lds16(pBh, d + 8192);
    gl_lds16(pBh + 32768, d + 12288);
    pAh += 32; pBh += 32;                        // next K-step
  };

  const int srow = tid >> 1, ssub = tid & 1;
  float tv[SC]; int ti[SC];
#pragma unroll
  for (int j = 0; j < SC; ++j) { tv[j] = INF; ti[j] = -1; }

  float sqr[4][4];
#pragma unroll
  for (int m = 0; m < 4; ++m)
#pragma unroll
    for (int j = 0; j < 4; ++j)
      sqr[m][j] = sq[row0 + wr * 64 + m * 16 + fq * 4 + j];

#pragma unroll 1
  for (int t = 0; t < 16; ++t) {
    const int ct = c0 + t * 128;
    float sqc[4];
#pragma unroll
    for (int n = 0; n < 4; ++n) sqc[n] = sq[ct + wc * 64 + n * 16 + fr];

    f32x4 acc[4][4];
#pragma unroll
    for (int m = 0; m < 4; ++m)
#pragma unroll
      for (int n = 0; n < 4; ++n) acc[m][n] = (f32x4){0.f, 0.f, 0.f, 0.f};

    stage(0);
    int cur = 0;
#pragma unroll 1
    for (int kt = 0; kt < 16; ++kt) {
      if (kt < 15) {
        stage(cur ^ 1);   // 8 outstanding
        VMCNT4;           // own 4 oldest = buf[cur] loads complete
      } else {
        VMCNT0;
      }
      __builtin_amdgcn_s_barrier();
      CFENCE;

      const short* Sb = (const short*)(smem + (cur << 14));
      s16x8 ah[4], bh[4];
#pragma unroll
      for (int m = 0; m < 4; ++m)
        ah[m] = *(const s16x8*)(Sb + (wr * 64 + m * 16 + fr) * 32 + sgx * 8);
#pragma unroll
      for (int n = 0; n < 4; ++n)
        bh[n] = *(const s16x8*)(Sb + 4096 + (wc * 64 + n * 16 + fr) * 32 + sgx * 8);
#pragma unroll
      for (int m = 0; m < 4; ++m)
#pragma unroll
        for (int n = 0; n < 4; ++n)
          acc[m][n] = __builtin_amdgcn_mfma_f32_16x16x32_bf16(ah[m], bh[n], acc[m][n], 0, 0, 0);

      LGKM0;
      __builtin_amdgcn_s_barrier();
      CFENCE;
      cur ^= 1;
    }
    pAh -= 512; pBh += 65024;

    // ---- epilogue: approx distances + per-row top-8 scan (f32x4 reads)
#pragma unroll 1
    for (int h = 0; h < 2; ++h) {
      if (wc == h) {
#pragma unroll
        for (int m = 0; m < 4; ++m)
#pragma unroll
          for (int n = 0; n < 4; ++n) {
            const int cl = n * 16 + fr;
            const int gcol = ct + h * 64 + cl;
            const int rbase = wr * 64 + m * 16 + fq * 4;
#pragma unroll
            for (int j = 0; j < 4; ++j) {
              float d2 = fmaf(-2.0f, acc[m][n][j], sqr[m][j] + sqc[n]);
              if (row0 + rbase + j == gcol) d2 = INF;   // exclude self
              Dt[(rbase + j) * 68 + cl] = d2;
            }
          }
      }
      __syncthreads();
      {
        float kth = tv[SC - 1];
        const int gb = ct + h * 64 + ssub * 32;
#pragma unroll 1
        for (int g = 0; g < 8; ++g) {
          const f32x4 dv = *(const f32x4*)&Dt[srow * 68 + ssub * 32 + g * 4];
#pragma unroll
          for (int i = 0; i < 4; ++i) {
            const float d2 = dv[i];
            if (d2 < kth) {
              const int gi = gb + g * 4 + i;
#pragma unroll
              for (int j = SC - 1; j >= 1; --j) {
                const bool ja = (tv[j] > d2), jb = (tv[j - 1] > d2);
                const float nv = jb ? tv[j - 1] : (ja ? d2 : tv[j]);
                const int ni = jb ? ti[j - 1] : (ja ? gi : ti[j]);
                tv[j] = nv; ti[j] = ni;
              }
              if (tv[0] > d2) { tv[0] = d2; ti[0] = gi; }
              kth = tv[SC - 1];
            }
          }
        }
      }
      __syncthreads();
    }
  }

  // ---- block end: merge 2 scanner lists per row -> per-split top-16 (raw d2)
#pragma unroll
  for (int j = 0; j < SC; ++j) {
    SV[srow * 16 + ssub * 8 + j] = tv[j];
    SI[srow * 16 + ssub * 8 + j] = ti[j];
  }
  __syncthreads();
  if (tid < 128) {
    const int grow = row0 + tid;
    const size_t pb = (((size_t)which * 4 + split) * N + grow) * NC;
    int p0 = 0, p1 = 0;
#pragma unroll
    for (int j = 0; j < NC; ++j) {
      const float v0 = (p0 < SC) ? SV[tid * 16 + p0] : INF;
      const float v1 = (p1 < SC) ? SV[tid * 16 + 8 + p1] : INF;
      const int i0 = (p0 < SC) ? SI[tid * 16 + p0] : 0x7fffffff;
      const int i1 = (p1 < SC) ? SI[tid * 16 + 8 + p1] : 0x7fffffff;
      const bool t0 = (v0 < v1) || (v0 == v1 && i0 < i1);
      pval[pb + j] = t0 ? v0 : v1;
      pidx[pb + j] = t0 ? i0 : i1;
      if (t0) ++p0; else ++p1;
    }
  }
}

// ---------------------------------------------------------------- merge 4 splits -> top-32 candidate indices
__global__ __launch_bounds__(256)
void k_cand(const float* __restrict__ pval, const int* __restrict__ pidx,
            int* __restrict__ cidx)
{
  const int flat = blockIdx.x * 256 + threadIdx.x;   // 0..16383
  const int which = flat >> 13, row = flat & (N - 1);
  const size_t b0 = (((size_t)which * 4 + 0) * N + row) * NC;
  const size_t b1 = (((size_t)which * 4 + 1) * N + row) * NC;
  const size_t b2 = (((size_t)which * 4 + 2) * N + row) * NC;
  const size_t b3 = (((size_t)which * 4 + 3) * N + row) * NC;
  float v0 = pval[b0], v1 = pval[b1], v2 = pval[b2], v3 = pval[b3];
  int i0 = pidx[b0], i1 = pidx[b1], i2 = pidx[b2], i3 = pidx[b3];
  int p0 = 0, p1 = 0, p2 = 0, p3 = 0;
  const size_t ob = ((size_t)which * N + row) * NCAND;
#pragma unroll 1
  for (int j = 0; j < NCAND; ++j) {
    const bool a01 = (v0 < v1) || (v0 == v1 && i0 < i1);
    const float va = a01 ? v0 : v1; const int ia = a01 ? i0 : i1;
    const bool a23 = (v2 < v3) || (v2 == v3 && i2 < i3);
    const float vb = a23 ? v2 : v3; const int ib = a23 ? i2 : i3;
    const bool ab = (va < vb) || (va == vb && ia < ib);
    cidx[ob + j] = ab ? ia : ib;
    if (ab) {
      if (a01) { ++p0; v0 = (p0 < NC) ? pval[b0 + p0] : INF; i0 = (p0 < NC) ? pidx[b0 + p0] : 0x7fffffff; }
      else     { ++p1; v1 = (p1 < NC) ? pval[b1 + p1] : INF; i1 = (p1 < NC) ? pidx[b1 + p1] : 0x7fffffff; }
    } else {
      if (a23) { ++p2; v2 = (p2 < NC) ? pval[b2 + p2] : INF; i2 = (p2 < NC) ? pidx[b2 + p2] : 0x7fffffff; }
      else     { ++p3; v3 = (p3 < NC) ? pval[b3 + p3] : INF; i3 = (p3 < NC) ? pidx[b3 + p3] : 0x7fffffff; }
    }
  }
}

// ---------------------------------------------------------------- exact f32 rescore of 32 candidates -> top-15
__global__ __launch_bounds__(256)
void k_rescore(const float* __restrict__ emb, const float* __restrict__ ref,
               const float* __restrict__ sqall, const int* __restrict__ cidx,
               float* __restrict__ knnd, int* __restrict__ knni)
{
  const int tid = threadIdx.x;
  const int lane = tid & 63, w = tid >> 6;
  const int flat = blockIdx.x * 4 + w;     // 0..16383
  const int which = flat >> 13, row = flat & (N - 1);
  const float* E = which ? ref : emb;
  const float* sq = sqall + which * N;
  const int* cb = cidx + ((size_t)which * N + row) * NCAND;

  // own row: 8 f32 per lane
  const float4* orow = (const float4*)(E + (size_t)row * D) + lane * 2;
  const float4 o0 = orow[0], o1 = orow[1];
  const float sqr = sq[row];

  u64 mykey = ~0ull;
#pragma unroll 1
  for (int c = 0; c < NCAND; ++c) {
    const int cl = cb[c];                          // uniform -> broadcast
    const float4* crow = (const float4*)(E + (size_t)cl * D) + lane * 2;
    const float4 c0 = crow[0], c1 = crow[1];
    float s = o0.x*c0.x + o0.y*c0.y + o0.z*c0.z + o0.w*c0.w
            + o1.x*c1.x + o1.y*c1.y + o1.z*c1.z + o1.w*c1.w;
#pragma unroll
    for (int o = 32; o; o >>= 1) s += __shfl_xor(s, o);
    float d2 = fmaf(-2.0f, s, sqr + sq[cl]);
    d2 = fmaxf(d2, 0.0f);                          // key-safe (sign bit)
    const u64 key = ((u64)__float_as_uint(d2) << 32) | (unsigned)cl;
    if (lane == c) mykey = key;
  }

  const size_t ob = ((size_t)which * N + row) * KNN;
#pragma unroll 1
  for (int r = 0; r < KNN; ++r) {
    u64 m = mykey;
#pragma unroll
    for (int o = 32; o; o >>= 1) {
      const u64 t2 = __shfl_xor(m, o);
      if (t2 < m) m = t2;
    }
    if (mykey == m) mykey = ~0ull;                 // unique (idx distinct)
    if (lane == 0) {
      const float d2v = __uint_as_float((unsigned)(m >> 32));
      knnd[ob + r] = (d2v > 0.f) ? sqrtf(fmaxf(d2v, 1e-24f)) : 0.f;
      knni[ob + r] = (int)(m & 0xffffffffu);
    }
  }
}

// ---------------------------------------------------------------- fallback: f32 VALU gram KNN
__global__ __launch_bounds__(256)
void k_knn_fb(const float* __restrict__ Ecur, const float* __restrict__ Eref,
              const float* __restrict__ sqall,
              float* __restrict__ knnd, int* __restrict__ knni)
{
  const int which = blockIdx.y;
  const float* E = which ? Eref : Ecur;
  const float* sq = sqall + which * N;
  float* outd = knnd + (size_t)which * N * KNN;
  int* outi = knni + (size_t)which * N * KNN;
  const int row0 = blockIdx.x * RB;

  __shared__ float As[RB][KB + 1];
  __shared__ float Bs[KB][CB + 4];
  __shared__ float Dtf[RB][CB + 1];
  __shared__ float topv[RB][KNN];
  __shared__ int topi[RB][KNN];

  const int tid = threadIdx.x;
  const int tx = tid & 15, ty = tid >> 4;

  if (tid < RB) {
#pragma unroll
    for (int j = 0; j < KNN; ++j) { topv[tid][j] = INF; topi[tid][j] = -1; }
  }

  for (int ct = 0; ct < N; ct += CB) {
    float acc[2][4] = {{0.f,0.f,0.f,0.f},{0.f,0.f,0.f,0.f}};
    for (int kt = 0; kt < D; kt += KB) {
      __syncthreads();
      {
        int r = tid >> 3, c4 = (tid & 7) << 2;
        const float4 v = *(const float4*)&E[(size_t)(row0 + r) * D + kt + c4];
        As[r][c4+0] = v.x; As[r][c4+1] = v.y; As[r][c4+2] = v.z; As[r][c4+3] = v.w;
      }
      {
        int k = tid & 31, cbase = tid >> 5;
#pragma unroll
        for (int i = 0; i < 8; ++i) {
          int c = cbase + (i << 3);
          Bs[k][c] = E[(size_t)(ct + c) * D + kt + k];
        }
      }
      __syncthreads();
#pragma unroll
      for (int k = 0; k < KB; ++k) {
        float a0 = As[2*ty + 0][k], a1 = As[2*ty + 1][k];
        float4 b = *(const float4*)&Bs[k][tx << 2];
        acc[0][0] = fmaf(a0, b.x, acc[0][0]); acc[0][1] = fmaf(a0, b.y, acc[0][1]);
        acc[0][2] = fmaf(a0, b.z, acc[0][2]); acc[0][3] = fmaf(a0, b.w, acc[0][3]);
        acc[1][0] = fmaf(a1, b.x, acc[1][0]); acc[1][1] = fmaf(a1, b.y, acc[1][1]);
        acc[1][2] = fmaf(a1, b.z, acc[1][2]); acc[1][3] = fmaf(a1, b.w, acc[1][3]);
      }
    }
    {
      float sr0 = sq[row0 + 2*ty + 0], sr1 = sq[row0 + 2*ty + 1];
#pragma unroll
      for (int c = 0; c < 4; ++c) {
        int gc = ct + (tx << 2) + c;
        float scv = sq[gc];
        float d20 = sr0 + scv - 2.0f * acc[0][c];
        float d21 = sr1 + scv - 2.0f * acc[1][c];
        float d0 = (d20 > 0.0f) ? sqrtf(fmaxf(d20, 1e-24f)) : 0.0f;
        float d1 = (d21 > 0.0f) ? sqrtf(fmaxf(d21, 1e-24f)) : 0.0f;
        if (gc == row0 + 2*ty + 0) d0 = INF;
        if (gc == row0 + 2*ty + 1) d1 = INF;
        Dtf[2*ty + 0][(tx << 2) + c] = d0;
        Dtf[2*ty + 1][(tx << 2) + c] = d1;
      }
    }
    __syncthreads();
    if (tid < RB) {
      float kth = topv[tid][KNN-1];
      for (int c = 0; c < CB; ++c) {
        float d = Dtf[tid][c];
        if (d < kth) {
          int gi = ct + c;
          int j = KNN - 1;
          while (j > 0 && topv[tid][j-1] > d) {
            topv[tid][j] = topv[tid][j-1]; topi[tid][j] = topi[tid][j-1]; --j;
          }
          topv[tid][j] = d; topi[tid][j] = gi;
          kth = topv[tid][KNN-1];
        }
      }
    }
    __syncthreads();
  }
  if (tid < RB) {
    int gr = row0 + tid;
#pragma unroll
    for (int j = 0; j < KNN; ++j) {
      outd[(size_t)gr * KNN + j] = topv[tid][j];
      outi[(size_t)gr * KNN + j] = topi[tid][j];
    }
  }
}

// ---------------------------------------------------------------- fused angular (ref pass + curr diff pass)
__global__ __launch_bounds__(256)
void k_ang2(const float* __restrict__ Ecur, const float* __restrict__ Eref,
            const int* __restrict__ knni, float* __restrict__ angpart)
{
  __shared__ float v[KNN][D];
  __shared__ float e[D];
  __shared__ float invn[KNN];
  __shared__ float cref[NPAIR];
  __shared__ float wpart[4];

  const int i = blockIdx.x;
  const int tid = threadIdx.x;
  const int lane = tid & 63;
  const int w = tid >> 6;

  float acc = 0.f;

#pragma unroll 1
  for (int pass = 0; pass < 2; ++pass) {
    const float* E = pass ? Ecur : Eref;
    const int* idx = knni + ((size_t)(pass ? 0 : 1) * N + i) * KNN;

    if (tid < 128)
      ((float4*)e)[tid] = ((const float4*)(E + (size_t)i * D))[tid];
    __syncthreads();

    for (int j = w; j < KNN; j += 4) {
      const float* src = E + (size_t)idx[j] * D;
      const int base = lane * 8;
      float4 x0 = *(const float4*)(src + base);
      float4 x1 = *(const float4*)(src + base + 4);
      float4 e0 = *(const float4*)(&e[base]);
      float4 e1 = *(const float4*)(&e[base + 4]);
      float d0 = x0.x-e0.x, d1 = x0.y-e0.y, d2 = x0.z-e0.z, d3 = x0.w-e0.w;
      float d4 = x1.x-e1.x, d5 = x1.y-e1.y, d6 = x1.z-e1.z, d7 = x1.w-e1.w;
      v[j][base+0]=d0; v[j][base+1]=d1; v[j][base+2]=d2; v[j][base+3]=d3;
      v[j][base+4]=d4; v[j][base+5]=d5; v[j][base+6]=d6; v[j][base+7]=d7;
      float s = d0*d0 + d1*d1 + d2*d2 + d3*d3 + d4*d4 + d5*d5 + d6*d6 + d7*d7;
#pragma unroll
      for (int o = 32; o; o >>= 1) s += __shfl_xor(s, o);
      if (lane == 0) invn[j] = 1.0f / fmaxf(sqrtf(s), 1e-12f);
    }
    __syncthreads();

    for (int p = w; p < NPAIR; p += 4) {
      int a = 0, q = p, rem = KNN - 1;
      while (q >= rem) { q -= rem; ++a; --rem; }
      int b = a + 1 + q;
      const float* va = v[a];
      const float* vb = v[b];
      const int base = lane * 8;
      float4 A0 = *(const float4*)(va + base);
      float4 A1 = *(const float4*)(va + base + 4);
      float4 B0 = *(const float4*)(vb + base);
      float4 B1 = *(const float4*)(vb + base + 4);
      float s = A0.x*B0.x + A0.y*B0.y + A0.z*B0.z + A0.w*B0.w
              + A1.x*B1.x + A1.y*B1.y + A1.z*B1.z + A1.w*B1.w;
#pragma unroll
      for (int o = 32; o; o >>= 1) s += __shfl_xor(s, o);
      if (lane == 0) {
        float cosv = s * invn[a] * invn[b];
        if (pass == 0) cref[p] = cosv;
        else { float dd = cosv - cref[p]; acc = fmaf(dd, dd, acc); }
      }
    }
    __syncthreads();
  }

  if (lane == 0) wpart[w] = acc;
  __syncthreads();
  if (tid == 0) angpart[i] = (wpart[0] + wpart[1]) + (wpart[2] + wpart[3]);
}

// ---------------------------------------------------------------- per-row stats
__global__ __launch_bounds__(256)
void k_stats(const float* __restrict__ knnd, float* __restrict__ dens,
             float* __restrict__ loss1part)
{
  __shared__ float red[256];
  int n = blockIdx.x * 256 + threadIdx.x;
  const float* dc = knnd + (size_t)n * KNN;
  const float* dr = knnd + (size_t)(N + n) * KNN;
  float mc = 0.f, mr = 0.f;
#pragma unroll
  for (int j = 0; j < KNN; ++j) { mc += dc[j]; mr += dr[j]; }
  mc *= (1.0f / KNN); mr *= (1.0f / KNN);
  float ic = 1.0f / (mc + EPSF);
  float ir = 1.0f / (mr + EPSF);
  float s = 0.f;
#pragma unroll
  for (int j = 0; j < KNN; ++j) {
    float t = dc[j] * ic - dr[j] * ir;
    s = fmaf(t, t, s);
  }
  dens[n] = ic;
  dens[N + n] = ir;
  red[threadIdx.x] = s;
  __syncthreads();
  for (int o = 128; o; o >>= 1) {
    if (threadIdx.x < o) red[threadIdx.x] += red[threadIdx.x + o];
    __syncthreads();
  }
  if (threadIdx.x == 0) loss1part[blockIdx.x] = red[0];
}

// ---------------------------------------------------------------- final combine
__global__ __launch_bounds__(256)
void k_final(const float* __restrict__ loss1part, const float* __restrict__ dens,
             const float* __restrict__ angpart, float* __restrict__ out)
{
  __shared__ float red[256];
  const int t = threadIdx.x;

  float sc = 0.f, sr = 0.f;
  for (int n = t; n < N; n += 256) { sc += dens[n]; sr += dens[N + n]; }
  red[t] = sc; __syncthreads();
  for (int o = 128; o; o >>= 1) { if (t < o) red[t] += red[t + o]; __syncthreads(); }
  float scm = red[0]; __syncthreads();
  red[t] = sr; __syncthreads();
  for (int o = 128; o; o >>= 1) { if (t < o) red[t] += red[t + o]; __syncthreads(); }
  float srm = red[0]; __syncthreads();

  float icm = 1.0f / (scm / (float)N + EPSF);
  float irm = 1.0f / (srm / (float)N + EPSF);

  float l2 = 0.f;
  for (int n = t; n < N; n += 256) {
    float dd = dens[n] * icm - dens[N + n] * irm;
    l2 = fmaf(dd, dd, l2);
  }
  red[t] = l2; __syncthreads();
  for (int o = 128; o; o >>= 1) { if (t < o) red[t] += red[t + o]; __syncthreads(); }
  float l2sum = red[0]; __syncthreads();

  float l1 = (t < 32) ? loss1part[t] : 0.f;
  red[t] = l1; __syncthreads();
  for (int o = 128; o; o >>= 1) { if (t < o) red[t] += red[t + o]; __syncthreads(); }
  float l1sum = red[0]; __syncthreads();

  float l3 = 0.f;
  for (int n = t; n < N; n += 256) l3 += angpart[n];
  red[t] = l3; __syncthreads();
  for (int o = 128; o; o >>= 1) { if (t < o) red[t] += red[t + o]; __syncthreads(); }
  float l3sum = red[0];

  if (t == 0) {
    out[0] = l1sum / (float)(N * KNN)
           + 0.5f * l2sum / (float)N
           + 0.5f * l3sum / (float)(N * NPAIR);
  }
}

// ---------------------------------------------------------------- launch
extern "C" void kernel_launch(void* const* d_in, const int* in_sizes, int n_in,
                              void* d_out, int out_size, void* d_ws, size_t ws_size,
                              hipStream_t stream)
{
  const float* emb = (const float*)d_in[0];
  const float* ref = (const float*)d_in[1];
  float* out = (float*)d_out;
  char* ws = (char*)d_ws;

  const size_t off_sq = 0;                                  // 2N f32
  const size_t off_hi = off_sq + (size_t)2 * N * 4;         // 2ND bf16 (hi only)

  const size_t m_off_pval = off_hi + (size_t)2 * N * D * 2;              // 2*4*N*16 f32
  const size_t m_off_pidx = m_off_pval + (size_t)2 * 4 * N * NC * 4;     // 2*4*N*16 i32
  const size_t m_off_cidx = m_off_pidx + (size_t)2 * 4 * N * NC * 4;     // 2*N*32 i32
  const size_t m_off_knnd = m_off_cidx + (size_t)2 * N * NCAND * 4;
  const size_t m_off_knni = m_off_knnd + (size_t)2 * N * KNN * 4;
  const size_t m_off_angp = m_off_knni + (size_t)2 * N * KNN * 4;
  const size_t m_off_dens = m_off_angp + (size_t)N * 4;
  const size_t m_off_l1   = m_off_dens + (size_t)2 * N * 4;
  const size_t NEED       = m_off_l1 + 4096;

  float* sq = (float*)(ws + off_sq);
  float* knnd; int* knni; float* angpart; float* dens; float* l1part;

  k_sqnorm<<<(2 * N) / 4, 256, 0, stream>>>(emb, ref, sq);

  if (ws_size >= NEED) {
    unsigned short* hi = (unsigned short*)(ws + off_hi);
    float* pval = (float*)(ws + m_off_pval);
    int* pidx = (int*)(ws + m_off_pidx);
    int* cidx = (int*)(ws + m_off_cidx);
    knnd = (float*)(ws + m_off_knnd);
    knni = (int*)(ws + m_off_knni);
    angpart = (float*)(ws + m_off_angp);
    dens = (float*)(ws + m_off_dens);
    l1part = (float*)(ws + m_off_l1);

    k_split_hi<<<(2 * N * D / 8) / 256, 256, 0, stream>>>(emb, ref, hi);
    k_knn1<<<dim3(N / 128, 4, 2), 256, 0, stream>>>(hi, sq, pval, pidx);
    k_cand<<<(2 * N) / 256, 256, 0, stream>>>(pval, pidx, cidx);
    k_rescore<<<(2 * N) / 4, 256, 0, stream>>>(emb, ref, sq, cidx, knnd, knni);
  } else {
    size_t o = off_hi;
    knnd = (float*)(ws + o); o += (size_t)2 * N * KNN * 4;
    knni = (int*)(ws + o);   o += (size_t)2 * N * KNN * 4;
    angpart = (float*)(ws + o); o += (size_t)N * 4;
    dens = (float*)(ws + o); o += (size_t)2 * N * 4;
    l1part = (float*)(ws + o);
    k_knn_fb<<<dim3(N / RB, 2), 256, 0, stream>>>(emb, ref, sq, knnd, knni);
  }

  k_ang2<<<N, 256, 0, stream>>>(emb, ref, knni, angpart);
  k_stats<<<N / 256, 256, 0, stream>>>(knnd, dens, l1part);
  k_final<<<1, 256, 0, stream>>>(l1part, dens, angpart, out);
}

// Round 10
// 547.045 us; speedup vs baseline: 2.4573x; 1.5018x over previous
//
#include <hip/hip_runtime.h>

#define N 8192
#define D 512
#define KNN 15
#define SC 8       // per-scanner register list
#define NC 16      // per-split candidate list (2 scanners merged)
#define NCAND 32   // rescored candidates per row
#define NPAIR 105
#define EPSF 1e-8f

#define RB 32
#define CB 64
#define KB 32

#define INF __int_as_float(0x7f800000)

typedef __attribute__((ext_vector_type(4))) float f32x4;
typedef __attribute__((ext_vector_type(8))) short s16x8;
typedef __attribute__((ext_vector_type(8))) unsigned short u16x8;
typedef unsigned long long u64;

typedef const unsigned int __attribute__((address_space(1)))* gp_t;
typedef unsigned int __attribute__((address_space(3)))* lp_t;

__device__ __forceinline__ void gl_lds16(const void* g, void* l) {
  __builtin_amdgcn_global_load_lds((gp_t)g, (lp_t)l, 16, 0, 0);
}

__device__ __forceinline__ unsigned short bf16_rne(float x) {
  unsigned int u = __float_as_uint(x);
  return (unsigned short)((u + 0x7fffu + ((u >> 16) & 1u)) >> 16);
}

#define VMCNT4 asm volatile("s_waitcnt vmcnt(4)" ::: "memory")
#define VMCNT0 asm volatile("s_waitcnt vmcnt(0)" ::: "memory")
#define LGKM0  asm volatile("s_waitcnt lgkmcnt(0)" ::: "memory")
#define CFENCE asm volatile("" ::: "memory")

// ---------------------------------------------------------------- sq norms
__global__ __launch_bounds__(256)
void k_sqnorm(const float* __restrict__ A, const float* __restrict__ B,
              float* __restrict__ sq)
{
  int tid = threadIdx.x;
  int lane = tid & 63;
  int row = blockIdx.x * 4 + (tid >> 6);          // 0 .. 2N-1
  const float* src = (row < N) ? (A + (size_t)row * D)
                               : (B + (size_t)(row - N) * D);
  const float4* s4 = (const float4*)src + lane * 2;
  float4 x0 = s4[0], x1 = s4[1];
  float s = x0.x*x0.x + x0.y*x0.y + x0.z*x0.z + x0.w*x0.w
          + x1.x*x1.x + x1.y*x1.y + x1.z*x1.z + x1.w*x1.w;
#pragma unroll
  for (int o = 32; o; o >>= 1) s += __shfl_xor(s, o);
  if (lane == 0) sq[row] = s;
}

// ---------------------------------------------------------------- bf16 hi split (no lo)
__global__ __launch_bounds__(256)
void k_split_hi(const float* __restrict__ A, const float* __restrict__ B,
                unsigned short* __restrict__ hi)
{
  size_t t = (size_t)blockIdx.x * 256 + threadIdx.x;
  size_t base = t * 8;
  const float* src = (base < (size_t)N * D) ? (A + base) : (B + (base - (size_t)N * D));
  float4 x0 = ((const float4*)src)[0];
  float4 x1 = ((const float4*)src)[1];
  float xs[8] = {x0.x, x0.y, x0.z, x0.w, x1.x, x1.y, x1.z, x1.w};
  u16x8 hv;
#pragma unroll
  for (int j = 0; j < 8; ++j) hv[j] = bf16_rne(xs[j]);
  *(u16x8*)(hi + base) = hv;
}

// ================================================================ stage 1:
// approx (hi-only) MFMA gram + per-split top-16 candidates. (unchanged R9)
__global__ __launch_bounds__(256, 2)
void k_knn1(const unsigned short* __restrict__ hi,
            const float* __restrict__ sqall,
            float* __restrict__ pval, int* __restrict__ pidx)
{
  __shared__ __align__(16) char smem[40960];
  float* Dt = (float*)smem;                 // [128][68]
  float* SV = (float*)smem;                 // [128][16]
  int*   SI = (int*)(smem + 8192);          // [128][16]

  const int tid = threadIdx.x;
  const int lane = tid & 63, w = tid >> 6;
  const int wr = w >> 1, wc = w & 1;
  const int fr = lane & 15, fq = lane >> 4;
  const int sgx = fq ^ ((fr >> 1) & 3);     // read-side seg swizzle

  const int rb = blockIdx.x, split = blockIdx.y, which = blockIdx.z;
  const int row0 = rb * 128;
  const int c0 = split * 2048;
  const unsigned short* Hi = hi + (size_t)which * N * D;
  const float* sq = sqall + which * N;

  const int rr = tid >> 2, sseg = tid & 3;
  const int ssg = sseg ^ ((rr >> 1) & 3);
  const unsigned short* pAh = Hi + (size_t)(row0 + rr) * D + ssg * 8;
  const unsigned short* pBh = Hi + (size_t)(c0 + rr) * D + ssg * 8;

  auto stage = [&](int sel) {
    char* d = smem + (sel << 14) + (w << 10);   // wave-uniform dest base
    gl_lds16(pAh, d);
    gl_lds16(pAh + 32768, d + 4096);            // rows +64 (+65536 B global)
    gl_lds16(pBh, d + 8192);
    gl_lds16(pBh + 32768, d + 12288);
    pAh += 32; pBh += 32;                        // next K-step
  };

  const int srow = tid >> 1, ssub = tid & 1;
  float tv[SC]; int ti[SC];
#pragma unroll
  for (int j = 0; j < SC; ++j) { tv[j] = INF; ti[j] = -1; }

  float sqr[4][4];
#pragma unroll
  for (int m = 0; m < 4; ++m)
#pragma unroll
    for (int j = 0; j < 4; ++j)
      sqr[m][j] = sq[row0 + wr * 64 + m * 16 + fq * 4 + j];

#pragma unroll 1
  for (int t = 0; t < 16; ++t) {
    const int ct = c0 + t * 128;
    float sqc[4];
#pragma unroll
    for (int n = 0; n < 4; ++n) sqc[n] = sq[ct + wc * 64 + n * 16 + fr];

    f32x4 acc[4][4];
#pragma unroll
    for (int m = 0; m < 4; ++m)
#pragma unroll
      for (int n = 0; n < 4; ++n) acc[m][n] = (f32x4){0.f, 0.f, 0.f, 0.f};

    stage(0);
    int cur = 0;
#pragma unroll 1
    for (int kt = 0; kt < 16; ++kt) {
      if (kt < 15) {
        stage(cur ^ 1);   // 8 outstanding
        VMCNT4;           // own 4 oldest = buf[cur] loads complete
      } else {
        VMCNT0;
      }
      __builtin_amdgcn_s_barrier();
      CFENCE;

      const short* Sb = (const short*)(smem + (cur << 14));
      s16x8 ah[4], bh[4];
#pragma unroll
      for (int m = 0; m < 4; ++m)
        ah[m] = *(const s16x8*)(Sb + (wr * 64 + m * 16 + fr) * 32 + sgx * 8);
#pragma unroll
      for (int n = 0; n < 4; ++n)
        bh[n] = *(const s16x8*)(Sb + 4096 + (wc * 64 + n * 16 + fr) * 32 + sgx * 8);
#pragma unroll
      for (int m = 0; m < 4; ++m)
#pragma unroll
        for (int n = 0; n < 4; ++n)
          acc[m][n] = __builtin_amdgcn_mfma_f32_16x16x32_bf16(ah[m], bh[n], acc[m][n], 0, 0, 0);

      LGKM0;
      __builtin_amdgcn_s_barrier();
      CFENCE;
      cur ^= 1;
    }
    pAh -= 512; pBh += 65024;

    // ---- epilogue: approx distances + per-row top-8 scan (f32x4 reads)
#pragma unroll 1
    for (int h = 0; h < 2; ++h) {
      if (wc == h) {
#pragma unroll
        for (int m = 0; m < 4; ++m)
#pragma unroll
          for (int n = 0; n < 4; ++n) {
            const int cl = n * 16 + fr;
            const int gcol = ct + h * 64 + cl;
            const int rbase = wr * 64 + m * 16 + fq * 4;
#pragma unroll
            for (int j = 0; j < 4; ++j) {
              float d2 = fmaf(-2.0f, acc[m][n][j], sqr[m][j] + sqc[n]);
              if (row0 + rbase + j == gcol) d2 = INF;   // exclude self
              Dt[(rbase + j) * 68 + cl] = d2;
            }
          }
      }
      __syncthreads();
      {
        float kth = tv[SC - 1];
        const int gb = ct + h * 64 + ssub * 32;
#pragma unroll 1
        for (int g = 0; g < 8; ++g) {
          const f32x4 dv = *(const f32x4*)&Dt[srow * 68 + ssub * 32 + g * 4];
#pragma unroll
          for (int i = 0; i < 4; ++i) {
            const float d2 = dv[i];
            if (d2 < kth) {
              const int gi = gb + g * 4 + i;
#pragma unroll
              for (int j = SC - 1; j >= 1; --j) {
                const bool ja = (tv[j] > d2), jb = (tv[j - 1] > d2);
                const float nv = jb ? tv[j - 1] : (ja ? d2 : tv[j]);
                const int ni = jb ? ti[j - 1] : (ja ? gi : ti[j]);
                tv[j] = nv; ti[j] = ni;
              }
              if (tv[0] > d2) { tv[0] = d2; ti[0] = gi; }
              kth = tv[SC - 1];
            }
          }
        }
      }
      __syncthreads();
    }
  }

  // ---- block end: merge 2 scanner lists per row -> per-split top-16 (raw d2)
#pragma unroll
  for (int j = 0; j < SC; ++j) {
    SV[srow * 16 + ssub * 8 + j] = tv[j];
    SI[srow * 16 + ssub * 8 + j] = ti[j];
  }
  __syncthreads();
  if (tid < 128) {
    const int grow = row0 + tid;
    const size_t pb = (((size_t)which * 4 + split) * N + grow) * NC;
    int p0 = 0, p1 = 0;
#pragma unroll
    for (int j = 0; j < NC; ++j) {
      const float v0 = (p0 < SC) ? SV[tid * 16 + p0] : INF;
      const float v1 = (p1 < SC) ? SV[tid * 16 + 8 + p1] : INF;
      const int i0 = (p0 < SC) ? SI[tid * 16 + p0] : 0x7fffffff;
      const int i1 = (p1 < SC) ? SI[tid * 16 + 8 + p1] : 0x7fffffff;
      const bool t0 = (v0 < v1) || (v0 == v1 && i0 < i1);
      pval[pb + j] = t0 ? v0 : v1;
      pidx[pb + j] = t0 ? i0 : i1;
      if (t0) ++p0; else ++p1;
    }
  }
}

// ---------------------------------------------------------------- merge 4 splits -> top-32 candidate indices
__global__ __launch_bounds__(256)
void k_cand(const float* __restrict__ pval, const int* __restrict__ pidx,
            int* __restrict__ cidx)
{
  const int flat = blockIdx.x * 256 + threadIdx.x;   // 0..16383
  const int which = flat >> 13, row = flat & (N - 1);
  const size_t b0 = (((size_t)which * 4 + 0) * N + row) * NC;
  const size_t b1 = (((size_t)which * 4 + 1) * N + row) * NC;
  const size_t b2 = (((size_t)which * 4 + 2) * N + row) * NC;
  const size_t b3 = (((size_t)which * 4 + 3) * N + row) * NC;
  float v0 = pval[b0], v1 = pval[b1], v2 = pval[b2], v3 = pval[b3];
  int i0 = pidx[b0], i1 = pidx[b1], i2 = pidx[b2], i3 = pidx[b3];
  int p0 = 0, p1 = 0, p2 = 0, p3 = 0;
  const size_t ob = ((size_t)which * N + row) * NCAND;
#pragma unroll 1
  for (int j = 0; j < NCAND; ++j) {
    const bool a01 = (v0 < v1) || (v0 == v1 && i0 < i1);
    const float va = a01 ? v0 : v1; const int ia = a01 ? i0 : i1;
    const bool a23 = (v2 < v3) || (v2 == v3 && i2 < i3);
    const float vb = a23 ? v2 : v3; const int ib = a23 ? i2 : i3;
    const bool ab = (va < vb) || (va == vb && ia < ib);
    cidx[ob + j] = ab ? ia : ib;
    if (ab) {
      if (a01) { ++p0; v0 = (p0 < NC) ? pval[b0 + p0] : INF; i0 = (p0 < NC) ? pidx[b0 + p0] : 0x7fffffff; }
      else     { ++p1; v1 = (p1 < NC) ? pval[b1 + p1] : INF; i1 = (p1 < NC) ? pidx[b1 + p1] : 0x7fffffff; }
    } else {
      if (a23) { ++p2; v2 = (p2 < NC) ? pval[b2 + p2] : INF; i2 = (p2 < NC) ? pidx[b2 + p2] : 0x7fffffff; }
      else     { ++p3; v3 = (p3 < NC) ? pval[b3 + p3] : INF; i3 = (p3 < NC) ? pidx[b3 + p3] : 0x7fffffff; }
    }
  }
}

// ---------------------------------------------------------------- exact f32 rescore of 32 candidates -> top-15
// unroll-4 dot phase (ILP) + 64-lane bitonic sort for selection
__global__ __launch_bounds__(256)
void k_rescore(const float* __restrict__ emb, const float* __restrict__ ref,
               const float* __restrict__ sqall, const int* __restrict__ cidx,
               float* __restrict__ knnd, int* __restrict__ knni)
{
  const int tid = threadIdx.x;
  const int lane = tid & 63, w = tid >> 6;
  const int flat = blockIdx.x * 4 + w;     // 0..16383
  const int which = flat >> 13, row = flat & (N - 1);
  const float* E = which ? ref : emb;
  const float* sq = sqall + which * N;
  const int* cb = cidx + ((size_t)which * N + row) * NCAND;

  const float4* orow = (const float4*)(E + (size_t)row * D) + lane * 2;
  const float4 o0 = orow[0], o1 = orow[1];
  const float sqr = sq[row];

  u64 mykey = ~0ull;
#pragma unroll 4
  for (int c = 0; c < NCAND; ++c) {
    const int cl = cb[c];                          // uniform -> broadcast
    const float4* crow = (const float4*)(E + (size_t)cl * D) + lane * 2;
    const float4 c0 = crow[0], c1 = crow[1];
    float s = o0.x*c0.x + o0.y*c0.y + o0.z*c0.z + o0.w*c0.w
            + o1.x*c1.x + o1.y*c1.y + o1.z*c1.z + o1.w*c1.w;
#pragma unroll
    for (int o = 32; o; o >>= 1) s += __shfl_xor(s, o);
    float d2 = fmaf(-2.0f, s, sqr + sq[cl]);
    d2 = fmaxf(d2, 0.0f);                          // key-safe (sign bit)
    const u64 key = ((u64)__float_as_uint(d2) << 32) | (unsigned)cl;
    if (lane == c) mykey = key;
  }

  // bitonic sort ascending across 64 lanes (lanes >= NCAND hold ~0ull)
#pragma unroll
  for (int k = 2; k <= 64; k <<= 1) {
#pragma unroll
    for (int j = k >> 1; j > 0; j >>= 1) {
      const u64 o = __shfl_xor(mykey, j);
      const bool up = ((lane & k) == 0);
      const bool lower = ((lane & j) == 0);
      const u64 mn = (mykey < o) ? mykey : o;
      const u64 mx = (mykey < o) ? o : mykey;
      mykey = (lower == up) ? mn : mx;
    }
  }

  const size_t ob = ((size_t)which * N + row) * KNN;
  if (lane < KNN) {
    const float d2v = __uint_as_float((unsigned)(mykey >> 32));
    knnd[ob + lane] = (d2v > 0.f) ? sqrtf(fmaxf(d2v, 1e-24f)) : 0.f;
    knni[ob + lane] = (int)(mykey & 0xffffffffu);
  }
}

// ---------------------------------------------------------------- fallback: f32 VALU gram KNN
__global__ __launch_bounds__(256)
void k_knn_fb(const float* __restrict__ Ecur, const float* __restrict__ Eref,
              const float* __restrict__ sqall,
              float* __restrict__ knnd, int* __restrict__ knni)
{
  const int which = blockIdx.y;
  const float* E = which ? Eref : Ecur;
  const float* sq = sqall + which * N;
  float* outd = knnd + (size_t)which * N * KNN;
  int* outi = knni + (size_t)which * N * KNN;
  const int row0 = blockIdx.x * RB;

  __shared__ float As[RB][KB + 1];
  __shared__ float Bs[KB][CB + 4];
  __shared__ float Dtf[RB][CB + 1];
  __shared__ float topv[RB][KNN];
  __shared__ int topi[RB][KNN];

  const int tid = threadIdx.x;
  const int tx = tid & 15, ty = tid >> 4;

  if (tid < RB) {
#pragma unroll
    for (int j = 0; j < KNN; ++j) { topv[tid][j] = INF; topi[tid][j] = -1; }
  }

  for (int ct = 0; ct < N; ct += CB) {
    float acc[2][4] = {{0.f,0.f,0.f,0.f},{0.f,0.f,0.f,0.f}};
    for (int kt = 0; kt < D; kt += KB) {
      __syncthreads();
      {
        int r = tid >> 3, c4 = (tid & 7) << 2;
        const float4 v = *(const float4*)&E[(size_t)(row0 + r) * D + kt + c4];
        As[r][c4+0] = v.x; As[r][c4+1] = v.y; As[r][c4+2] = v.z; As[r][c4+3] = v.w;
      }
      {
        int k = tid & 31, cbase = tid >> 5;
#pragma unroll
        for (int i = 0; i < 8; ++i) {
          int c = cbase + (i << 3);
          Bs[k][c] = E[(size_t)(ct + c) * D + kt + k];
        }
      }
      __syncthreads();
#pragma unroll
      for (int k = 0; k < KB; ++k) {
        float a0 = As[2*ty + 0][k], a1 = As[2*ty + 1][k];
        float4 b = *(const float4*)&Bs[k][tx << 2];
        acc[0][0] = fmaf(a0, b.x, acc[0][0]); acc[0][1] = fmaf(a0, b.y, acc[0][1]);
        acc[0][2] = fmaf(a0, b.z, acc[0][2]); acc[0][3] = fmaf(a0, b.w, acc[0][3]);
        acc[1][0] = fmaf(a1, b.x, acc[1][0]); acc[1][1] = fmaf(a1, b.y, acc[1][1]);
        acc[1][2] = fmaf(a1, b.z, acc[1][2]); acc[1][3] = fmaf(a1, b.w, acc[1][3]);
      }
    }
    {
      float sr0 = sq[row0 + 2*ty + 0], sr1 = sq[row0 + 2*ty + 1];
#pragma unroll
      for (int c = 0; c < 4; ++c) {
        int gc = ct + (tx << 2) + c;
        float scv = sq[gc];
        float d20 = sr0 + scv - 2.0f * acc[0][c];
        float d21 = sr1 + scv - 2.0f * acc[1][c];
        float d0 = (d20 > 0.0f) ? sqrtf(fmaxf(d20, 1e-24f)) : 0.0f;
        float d1 = (d21 > 0.0f) ? sqrtf(fmaxf(d21, 1e-24f)) : 0.0f;
        if (gc == row0 + 2*ty + 0) d0 = INF;
        if (gc == row0 + 2*ty + 1) d1 = INF;
        Dtf[2*ty + 0][(tx << 2) + c] = d0;
        Dtf[2*ty + 1][(tx << 2) + c] = d1;
      }
    }
    __syncthreads();
    if (tid < RB) {
      float kth = topv[tid][KNN-1];
      for (int c = 0; c < CB; ++c) {
        float d = Dtf[tid][c];
        if (d < kth) {
          int gi = ct + c;
          int j = KNN - 1;
          while (j > 0 && topv[tid][j-1] > d) {
            topv[tid][j] = topv[tid][j-1]; topi[tid][j] = topi[tid][j-1]; --j;
          }
          topv[tid][j] = d; topi[tid][j] = gi;
          kth = topv[tid][KNN-1];
        }
      }
    }
    __syncthreads();
  }
  if (tid < RB) {
    int gr = row0 + tid;
#pragma unroll
    for (int j = 0; j < KNN; ++j) {
      outd[(size_t)gr * KNN + j] = topv[tid][j];
      outi[(size_t)gr * KNN + j] = topi[tid][j];
    }
  }
}

// ---------------------------------------------------------------- angular via per-point MFMA gram
// G = V V^T (V = 15x512 bf16 diff vectors, row 15 zero); norms from diag(G).
__global__ __launch_bounds__(256)
void k_ang3(const float* __restrict__ Ecur, const float* __restrict__ Eref,
            const int* __restrict__ knni, float* __restrict__ angpart)
{
  __shared__ __align__(16) short Vb[16][520];   // 16640 B, pad -> bank-clean frags
  __shared__ float Gp[4][256];
  __shared__ float G[256];
  __shared__ float invn[16];
  __shared__ float cref[NPAIR];
  __shared__ float red2[256];

  const int i = blockIdx.x;
  const int tid = threadIdx.x;
  const int lane = tid & 63;
  const int w = tid >> 6;
  const int base = lane * 8;

  float acc = 0.f;

#pragma unroll 1
  for (int pass = 0; pass < 2; ++pass) {
    const float* E = pass ? Ecur : Eref;
    const int* idx = knni + ((size_t)(pass ? 0 : 1) * N + i) * KNN;

    // own-row slice in registers
    const float4* er = (const float4*)(E + (size_t)i * D) + lane * 2;
    const float4 e0 = er[0], e1 = er[1];

    // build bf16 difference rows (wave w: j = w, w+4, ...; j==15 zero-pad)
#pragma unroll 1
    for (int j = w; j < 16; j += 4) {
      u16x8 hv;
      if (j < 15) {
        const float* src = E + (size_t)idx[j] * D;
        const float4 x0 = *(const float4*)(src + base);
        const float4 x1 = *(const float4*)(src + base + 4);
        const float dd[8] = {x0.x-e0.x, x0.y-e0.y, x0.z-e0.z, x0.w-e0.w,
                             x1.x-e1.x, x1.y-e1.y, x1.z-e1.z, x1.w-e1.w};
#pragma unroll
        for (int q = 0; q < 8; ++q) hv[q] = bf16_rne(dd[q]);
      } else {
#pragma unroll
        for (int q = 0; q < 8; ++q) hv[q] = 0;
      }
      *(u16x8*)&Vb[j][base] = hv;
    }
    __syncthreads();

    // gram: wave w covers K-slice [w*128, w*128+128) via 4 MFMA (A-frag == B-frag)
    {
      const int r = lane & 15, fq = lane >> 4;
      f32x4 g = (f32x4){0.f, 0.f, 0.f, 0.f};
#pragma unroll
      for (int s = 0; s < 4; ++s) {
        const s16x8 f = *(const s16x8*)&Vb[r][w * 128 + s * 32 + fq * 8];
        g = __builtin_amdgcn_mfma_f32_16x16x32_bf16(f, f, g, 0, 0, 0);
      }
#pragma unroll
      for (int r2 = 0; r2 < 4; ++r2)
        Gp[w][(fq * 4 + r2) * 16 + r] = g[r2];   // D: row=(fq*4+r2), col=r
    }
    __syncthreads();

    G[tid] = Gp[0][tid] + Gp[1][tid] + Gp[2][tid] + Gp[3][tid];
    __syncthreads();
    if (tid < 16) invn[tid] = 1.0f / fmaxf(sqrtf(G[tid * 17]), 1e-12f);
    __syncthreads();

    if (tid < NPAIR) {
      int a = 0, q = tid, rem = KNN - 1;
      while (q >= rem) { q -= rem; ++a; --rem; }
      const int b = a + 1 + q;
      const float cosv = G[a * 16 + b] * invn[a] * invn[b];
      if (pass == 0) cref[tid] = cosv;
      else { const float dd = cosv - cref[tid]; acc = dd * dd; }
    }
    __syncthreads();
  }

  red2[tid] = acc;
  __syncthreads();
  for (int o = 128; o; o >>= 1) {
    if (tid < o) red2[tid] += red2[tid + o];
    __syncthreads();
  }
  if (tid == 0) angpart[i] = red2[0];
}

// ---------------------------------------------------------------- per-row stats
__global__ __launch_bounds__(256)
void k_stats(const float* __restrict__ knnd, float* __restrict__ dens,
             float* __restrict__ loss1part)
{
  __shared__ float red[256];
  int n = blockIdx.x * 256 + threadIdx.x;
  const float* dc = knnd + (size_t)n * KNN;
  const float* dr = knnd + (size_t)(N + n) * KNN;
  float mc = 0.f, mr = 0.f;
#pragma unroll
  for (int j = 0; j < KNN; ++j) { mc += dc[j]; mr += dr[j]; }
  mc *= (1.0f / KNN); mr *= (1.0f / KNN);
  float ic = 1.0f / (mc + EPSF);
  float ir = 1.0f / (mr + EPSF);
  float s = 0.f;
#pragma unroll
  for (int j = 0; j < KNN; ++j) {
    float t = dc[j] * ic - dr[j] * ir;
    s = fmaf(t, t, s);
  }
  dens[n] = ic;
  dens[N + n] = ir;
  red[threadIdx.x] = s;
  __syncthreads();
  for (int o = 128; o; o >>= 1) {
    if (threadIdx.x < o) red[threadIdx.x] += red[threadIdx.x + o];
    __syncthreads();
  }
  if (threadIdx.x == 0) loss1part[blockIdx.x] = red[0];
}

// ---------------------------------------------------------------- final combine
__global__ __launch_bounds__(256)
void k_final(const float* __restrict__ loss1part, const float* __restrict__ dens,
             const float* __restrict__ angpart, float* __restrict__ out)
{
  __shared__ float red[256];
  const int t = threadIdx.x;

  float sc = 0.f, sr = 0.f;
  for (int n = t; n < N; n += 256) { sc += dens[n]; sr += dens[N + n]; }
  red[t] = sc; __syncthreads();
  for (int o = 128; o; o >>= 1) { if (t < o) red[t] += red[t + o]; __syncthreads(); }
  float scm = red[0]; __syncthreads();
  red[t] = sr; __syncthreads();
  for (int o = 128; o; o >>= 1) { if (t < o) red[t] += red[t + o]; __syncthreads(); }
  float srm = red[0]; __syncthreads();

  float icm = 1.0f / (scm / (float)N + EPSF);
  float irm = 1.0f / (srm / (float)N + EPSF);

  float l2 = 0.f;
  for (int n = t; n < N; n += 256) {
    float dd = dens[n] * icm - dens[N + n] * irm;
    l2 = fmaf(dd, dd, l2);
  }
  red[t] = l2; __syncthreads();
  for (int o = 128; o; o >>= 1) { if (t < o) red[t] += red[t + o]; __syncthreads(); }
  float l2sum = red[0]; __syncthreads();

  float l1 = (t < 32) ? loss1part[t] : 0.f;
  red[t] = l1; __syncthreads();
  for (int o = 128; o; o >>= 1) { if (t < o) red[t] += red[t + o]; __syncthreads(); }
  float l1sum = red[0]; __syncthreads();

  float l3 = 0.f;
  for (int n = t; n < N; n += 256) l3 += angpart[n];
  red[t] = l3; __syncthreads();
  for (int o = 128; o; o >>= 1) { if (t < o) red[t] += red[t + o]; __syncthreads(); }
  float l3sum = red[0];

  if (t == 0) {
    out[0] = l1sum / (float)(N * KNN)
           + 0.5f * l2sum / (float)N
           + 0.5f * l3sum / (float)(N * NPAIR);
  }
}

// ---------------------------------------------------------------- launch
extern "C" void kernel_launch(void* const* d_in, const int* in_sizes, int n_in,
                              void* d_out, int out_size, void* d_ws, size_t ws_size,
                              hipStream_t stream)
{
  const float* emb = (const float*)d_in[0];
  const float* ref = (const float*)d_in[1];
  float* out = (float*)d_out;
  char* ws = (char*)d_ws;

  const size_t off_sq = 0;                                  // 2N f32
  const size_t off_hi = off_sq + (size_t)2 * N * 4;         // 2ND bf16 (hi only)

  const size_t m_off_pval = off_hi + (size_t)2 * N * D * 2;              // 2*4*N*16 f32
  const size_t m_off_pidx = m_off_pval + (size_t)2 * 4 * N * NC * 4;     // 2*4*N*16 i32
  const size_t m_off_cidx = m_off_pidx + (size_t)2 * 4 * N * NC * 4;     // 2*N*32 i32
  const size_t m_off_knnd = m_off_cidx + (size_t)2 * N * NCAND * 4;
  const size_t m_off_knni = m_off_knnd + (size_t)2 * N * KNN * 4;
  const size_t m_off_angp = m_off_knni + (size_t)2 * N * KNN * 4;
  const size_t m_off_dens = m_off_angp + (size_t)N * 4;
  const size_t m_off_l1   = m_off_dens + (size_t)2 * N * 4;
  const size_t NEED       = m_off_l1 + 4096;

  float* sq = (float*)(ws + off_sq);
  float* knnd; int* knni; float* angpart; float* dens; float* l1part;

  k_sqnorm<<<(2 * N) / 4, 256, 0, stream>>>(emb, ref, sq);

  if (ws_size >= NEED) {
    unsigned short* hi = (unsigned short*)(ws + off_hi);
    float* pval = (float*)(ws + m_off_pval);
    int* pidx = (int*)(ws + m_off_pidx);
    int* cidx = (int*)(ws + m_off_cidx);
    knnd = (float*)(ws + m_off_knnd);
    knni = (int*)(ws + m_off_knni);
    angpart = (float*)(ws + m_off_angp);
    dens = (float*)(ws + m_off_dens);
    l1part = (float*)(ws + m_off_l1);

    k_split_hi<<<(2 * N * D / 8) / 256, 256, 0, stream>>>(emb, ref, hi);
    k_knn1<<<dim3(N / 128, 4, 2), 256, 0, stream>>>(hi, sq, pval, pidx);
    k_cand<<<(2 * N) / 256, 256, 0, stream>>>(pval, pidx, cidx);
    k_rescore<<<(2 * N) / 4, 256, 0, stream>>>(emb, ref, sq, cidx, knnd, knni);
  } else {
    size_t o = off_hi;
    knnd = (float*)(ws + o); o += (size_t)2 * N * KNN * 4;
    knni = (int*)(ws + o);   o += (size_t)2 * N * KNN * 4;
    angpart = (float*)(ws + o); o += (size_t)N * 4;
    dens = (float*)(ws + o); o += (size_t)2 * N * 4;
    l1part = (float*)(ws + o);
    k_knn_fb<<<dim3(N / RB, 2), 256, 0, stream>>>(emb, ref, sq, knnd, knni);
  }

  k_ang3<<<N, 256, 0, stream>>>(emb, ref, knni, angpart);
  k_stats<<<N / 256, 256, 0, stream>>>(knnd, dens, l1part);
  k_final<<<1, 256, 0, stream>>>(l1part, dens, angpart, out);
}

// Round 11
// 396.086 us; speedup vs baseline: 3.3938x; 1.3811x over previous
//
#include <hip/hip_runtime.h>

#define N 8192
#define D 512
#define KNN 15
#define SC 8       // per-scanner register list
#define NC 16      // per-split candidate list (2 scanners merged)
#define SPLITS 8
#define NCAND 32   // rescored candidates per row
#define NPAIR 105
#define EPSF 1e-8f

#define RB 32
#define CB 64
#define KB 32

#define INF __int_as_float(0x7f800000)

typedef __attribute__((ext_vector_type(4))) float f32x4;
typedef __attribute__((ext_vector_type(8))) short s16x8;
typedef __attribute__((ext_vector_type(8))) unsigned short u16x8;
typedef unsigned long long u64;

typedef const unsigned int __attribute__((address_space(1)))* gp_t;
typedef unsigned int __attribute__((address_space(3)))* lp_t;

__device__ __forceinline__ void gl_lds16(const void* g, void* l) {
  __builtin_amdgcn_global_load_lds((gp_t)g, (lp_t)l, 16, 0, 0);
}

__device__ __forceinline__ unsigned short bf16_rne(float x) {
  unsigned int u = __float_as_uint(x);
  return (unsigned short)((u + 0x7fffu + ((u >> 16) & 1u)) >> 16);
}

#define VMCNT4 asm volatile("s_waitcnt vmcnt(4)" ::: "memory")
#define VMCNT0 asm volatile("s_waitcnt vmcnt(0)" ::: "memory")
#define LGKM0  asm volatile("s_waitcnt lgkmcnt(0)" ::: "memory")
#define CFENCE asm volatile("" ::: "memory")

// ---------------------------------------------------------------- sq norms
__global__ __launch_bounds__(256)
void k_sqnorm(const float* __restrict__ A, const float* __restrict__ B,
              float* __restrict__ sq)
{
  int tid = threadIdx.x;
  int lane = tid & 63;
  int row = blockIdx.x * 4 + (tid >> 6);          // 0 .. 2N-1
  const float* src = (row < N) ? (A + (size_t)row * D)
                               : (B + (size_t)(row - N) * D);
  const float4* s4 = (const float4*)src + lane * 2;
  float4 x0 = s4[0], x1 = s4[1];
  float s = x0.x*x0.x + x0.y*x0.y + x0.z*x0.z + x0.w*x0.w
          + x1.x*x1.x + x1.y*x1.y + x1.z*x1.z + x1.w*x1.w;
#pragma unroll
  for (int o = 32; o; o >>= 1) s += __shfl_xor(s, o);
  if (lane == 0) sq[row] = s;
}

// ---------------------------------------------------------------- bf16 hi split
__global__ __launch_bounds__(256)
void k_split_hi(const float* __restrict__ A, const float* __restrict__ B,
                unsigned short* __restrict__ hi)
{
  size_t t = (size_t)blockIdx.x * 256 + threadIdx.x;
  size_t base = t * 8;
  const float* src = (base < (size_t)N * D) ? (A + base) : (B + (base - (size_t)N * D));
  float4 x0 = ((const float4*)src)[0];
  float4 x1 = ((const float4*)src)[1];
  float xs[8] = {x0.x, x0.y, x0.z, x0.w, x1.x, x1.y, x1.z, x1.w};
  u16x8 hv;
#pragma unroll
  for (int j = 0; j < 8; ++j) hv[j] = bf16_rne(xs[j]);
  *(u16x8*)(hi + base) = hv;
}

// ================================================================ stage 1:
// approx (hi-only) MFMA gram + per-split top-16 candidate KEYS.
// key u32 = (f32bits(max(d2,0)) & ~1023) | col_in_split  (col < 1024).
// 8 column splits (1024 cols each) -> 1024 blocks -> 4 blocks/CU.
// LDS 40960 B: stage dbuf 2x16KB at [0,32768); Dt[128][68] overlay;
// SK[128][16] u32 overlay for the block-end merge.
__global__ __launch_bounds__(256, 4)
void k_knn1(const unsigned short* __restrict__ hi,
            const float* __restrict__ sqall,
            unsigned* __restrict__ pk)
{
  __shared__ __align__(16) char smem[40960];
  float* Dt = (float*)smem;                 // [128][68]
  unsigned* SK = (unsigned*)smem;           // [128][16]

  const int tid = threadIdx.x;
  const int lane = tid & 63, w = tid >> 6;
  const int wr = w >> 1, wc = w & 1;
  const int fr = lane & 15, fq = lane >> 4;
  const int sgx = fq ^ ((fr >> 1) & 3);     // read-side seg swizzle

  const int rb = blockIdx.x, split = blockIdx.y, which = blockIdx.z;
  const int row0 = rb * 128;
  const int c0 = split * 1024;
  const unsigned short* Hi = hi + (size_t)which * N * D;
  const float* sq = sqall + which * N;

  const int rr = tid >> 2, sseg = tid & 3;
  const int ssg = sseg ^ ((rr >> 1) & 3);
  const unsigned short* pAh = Hi + (size_t)(row0 + rr) * D + ssg * 8;
  const unsigned short* pBh = Hi + (size_t)(c0 + rr) * D + ssg * 8;

  auto stage = [&](int sel) {
    char* d = smem + (sel << 14) + (w << 10);   // wave-uniform dest base
    gl_lds16(pAh, d);
    gl_lds16(pAh + 32768, d + 4096);            // rows +64 (+65536 B global)
    gl_lds16(pBh, d + 8192);
    gl_lds16(pBh + 32768, d + 12288);
    pAh += 32; pBh += 32;                        // next K-step
  };

  const int srow = tid >> 1, ssub = tid & 1;
  unsigned tv[SC];
#pragma unroll
  for (int j = 0; j < SC; ++j) tv[j] = 0xFFFFFFFFu;

  float sqr[4][4];
#pragma unroll
  for (int m = 0; m < 4; ++m)
#pragma unroll
    for (int j = 0; j < 4; ++j)
      sqr[m][j] = sq[row0 + wr * 64 + m * 16 + fq * 4 + j];

#pragma unroll 1
  for (int t = 0; t < 8; ++t) {
    const int ct = c0 + t * 128;
    float sqc[4];
#pragma unroll
    for (int n = 0; n < 4; ++n) sqc[n] = sq[ct + wc * 64 + n * 16 + fr];

    f32x4 acc[4][4];
#pragma unroll
    for (int m = 0; m < 4; ++m)
#pragma unroll
      for (int n = 0; n < 4; ++n) acc[m][n] = (f32x4){0.f, 0.f, 0.f, 0.f};

    stage(0);
    int cur = 0;
#pragma unroll 1
    for (int kt = 0; kt < 16; ++kt) {
      if (kt < 15) {
        stage(cur ^ 1);   // 8 outstanding
        VMCNT4;           // own 4 oldest = buf[cur] loads complete
      } else {
        VMCNT0;
      }
      __builtin_amdgcn_s_barrier();
      CFENCE;

      const short* Sb = (const short*)(smem + (cur << 14));
      s16x8 ah[4], bh[4];
#pragma unroll
      for (int m = 0; m < 4; ++m)
        ah[m] = *(const s16x8*)(Sb + (wr * 64 + m * 16 + fr) * 32 + sgx * 8);
#pragma unroll
      for (int n = 0; n < 4; ++n)
        bh[n] = *(const s16x8*)(Sb + 4096 + (wc * 64 + n * 16 + fr) * 32 + sgx * 8);
#pragma unroll
      for (int m = 0; m < 4; ++m)
#pragma unroll
        for (int n = 0; n < 4; ++n)
          acc[m][n] = __builtin_amdgcn_mfma_f32_16x16x32_bf16(ah[m], bh[n], acc[m][n], 0, 0, 0);

      LGKM0;
      __builtin_amdgcn_s_barrier();
      CFENCE;
      cur ^= 1;
    }
    pAh -= 512; pBh += 65024;

    // ---- epilogue: raw d2 into Dt, then branchless-key top-8 scan
#pragma unroll 1
    for (int h = 0; h < 2; ++h) {
      if (wc == h) {
#pragma unroll
        for (int m = 0; m < 4; ++m)
#pragma unroll
          for (int n = 0; n < 4; ++n) {
            const int cl = n * 16 + fr;
            const int gcol = ct + h * 64 + cl;
            const int rbase = wr * 64 + m * 16 + fq * 4;
#pragma unroll
            for (int j = 0; j < 4; ++j) {
              float d2 = fmaf(-2.0f, acc[m][n][j], sqr[m][j] + sqc[n]);
              if (row0 + rbase + j == gcol) d2 = INF;   // exclude self
              Dt[(rbase + j) * 68 + cl] = d2;
            }
          }
      }
      __syncthreads();
      {
        unsigned kth = tv[SC - 1];
        const int lb = t * 128 + h * 64 + ssub * 32;     // local col base
#pragma unroll 1
        for (int g = 0; g < 8; ++g) {
          const f32x4 dv = *(const f32x4*)&Dt[srow * 68 + ssub * 32 + g * 4];
#pragma unroll
          for (int i = 0; i < 4; ++i) {
            const float d2c = fmaxf(dv[i], 0.0f);
            unsigned key = (__float_as_uint(d2c) & ~1023u) | (unsigned)(lb + g * 4 + i);
            if (key < kth) {
#pragma unroll
              for (int j = 0; j < SC; ++j) {
                const unsigned lo = min(tv[j], key);
                key = max(tv[j], key);
                tv[j] = lo;
              }
              kth = tv[SC - 1];
            }
          }
        }
      }
      __syncthreads();
    }
  }

  // ---- block end: merge 2 sorted scanner lists per row -> sorted top-16 keys
#pragma unroll
  for (int j = 0; j < SC; ++j) SK[srow * 16 + ssub * 8 + j] = tv[j];
  __syncthreads();
  if (tid < 128) {
    const int grow = row0 + tid;
    const size_t pb = (((size_t)which * SPLITS + split) * N + grow) * NC;
    int p0 = 0, p1 = 0;
#pragma unroll
    for (int j = 0; j < NC; ++j) {
      const unsigned a = (p0 < SC) ? SK[tid * 16 + p0] : 0xFFFFFFFFu;
      const unsigned b = (p1 < SC) ? SK[tid * 16 + 8 + p1] : 0xFFFFFFFFu;
      const bool ta = a <= b;
      pk[pb + j] = ta ? a : b;
      if (ta) ++p0; else ++p1;
    }
  }
}

// ---------------------------------------------------------------- merge 8 split key-lists -> top-32 candidate indices
__global__ __launch_bounds__(256)
void k_cand(const unsigned* __restrict__ pk, int* __restrict__ cidx)
{
  const int flat = blockIdx.x * 256 + threadIdx.x;   // 0..16383
  const int which = flat >> 13, row = flat & (N - 1);
  const size_t b0 = (((size_t)which * SPLITS + 0) * N + row) * NC;
  const size_t b1 = (((size_t)which * SPLITS + 1) * N + row) * NC;
  const size_t b2 = (((size_t)which * SPLITS + 2) * N + row) * NC;
  const size_t b3 = (((size_t)which * SPLITS + 3) * N + row) * NC;
  const size_t b4 = (((size_t)which * SPLITS + 4) * N + row) * NC;
  const size_t b5 = (((size_t)which * SPLITS + 5) * N + row) * NC;
  const size_t b6 = (((size_t)which * SPLITS + 6) * N + row) * NC;
  const size_t b7 = (((size_t)which * SPLITS + 7) * N + row) * NC;
  unsigned v0 = pk[b0], v1 = pk[b1], v2 = pk[b2], v3 = pk[b3];
  unsigned v4 = pk[b4], v5 = pk[b5], v6 = pk[b6], v7 = pk[b7];
  int p0 = 0, p1 = 0, p2 = 0, p3 = 0, p4 = 0, p5 = 0, p6 = 0, p7 = 0;
  const size_t ob = ((size_t)which * N + row) * NCAND;
#pragma unroll 1
  for (int j = 0; j < NCAND; ++j) {
    const bool a01 = v0 <= v1; const unsigned m01 = a01 ? v0 : v1; const int s01 = a01 ? 0 : 1;
    const bool a23 = v2 <= v3; const unsigned m23 = a23 ? v2 : v3; const int s23 = a23 ? 2 : 3;
    const bool a45 = v4 <= v5; const unsigned m45 = a45 ? v4 : v5; const int s45 = a45 ? 4 : 5;
    const bool a67 = v6 <= v7; const unsigned m67 = a67 ? v6 : v7; const int s67 = a67 ? 6 : 7;
    const bool qA = m01 <= m23; const unsigned mA = qA ? m01 : m23; const int sA = qA ? s01 : s23;
    const bool qB = m45 <= m67; const unsigned mB = qB ? m45 : m67; const int sB = qB ? s45 : s67;
    const bool qf = mA <= mB;  const unsigned m = qf ? mA : mB;    const int sw = qf ? sA : sB;
    cidx[ob + j] = (sw << 10) | (int)(m & 1023u);
    if      (sw == 0) { ++p0; v0 = (p0 < NC) ? pk[b0 + p0] : 0xFFFFFFFFu; }
    else if (sw == 1) { ++p1; v1 = (p1 < NC) ? pk[b1 + p1] : 0xFFFFFFFFu; }
    else if (sw == 2) { ++p2; v2 = (p2 < NC) ? pk[b2 + p2] : 0xFFFFFFFFu; }
    else if (sw == 3) { ++p3; v3 = (p3 < NC) ? pk[b3 + p3] : 0xFFFFFFFFu; }
    else if (sw == 4) { ++p4; v4 = (p4 < NC) ? pk[b4 + p4] : 0xFFFFFFFFu; }
    else if (sw == 5) { ++p5; v5 = (p5 < NC) ? pk[b5 + p5] : 0xFFFFFFFFu; }
    else if (sw == 6) { ++p6; v6 = (p6 < NC) ? pk[b6 + p6] : 0xFFFFFFFFu; }
    else              { ++p7; v7 = (p7 < NC) ? pk[b7 + p7] : 0xFFFFFFFFu; }
  }
}

// ---------------------------------------------------------------- exact f32 rescore of 32 candidates -> top-15
__global__ __launch_bounds__(256)
void k_rescore(const float* __restrict__ emb, const float* __restrict__ ref,
               const float* __restrict__ sqall, const int* __restrict__ cidx,
               float* __restrict__ knnd, int* __restrict__ knni)
{
  const int tid = threadIdx.x;
  const int lane = tid & 63, w = tid >> 6;
  const int flat = blockIdx.x * 4 + w;     // 0..16383
  const int which = flat >> 13, row = flat & (N - 1);
  const float* E = which ? ref : emb;
  const float* sq = sqall + which * N;
  const int* cb = cidx + ((size_t)which * N + row) * NCAND;

  const float4* orow = (const float4*)(E + (size_t)row * D) + lane * 2;
  const float4 o0 = orow[0], o1 = orow[1];
  const float sqr = sq[row];

  u64 mykey = ~0ull;
#pragma unroll 4
  for (int c = 0; c < NCAND; ++c) {
    const int cl = cb[c];                          // uniform -> broadcast
    const float4* crow = (const float4*)(E + (size_t)cl * D) + lane * 2;
    const float4 c0 = crow[0], c1 = crow[1];
    float s = o0.x*c0.x + o0.y*c0.y + o0.z*c0.z + o0.w*c0.w
            + o1.x*c1.x + o1.y*c1.y + o1.z*c1.z + o1.w*c1.w;
#pragma unroll
    for (int o = 32; o; o >>= 1) s += __shfl_xor(s, o);
    float d2 = fmaf(-2.0f, s, sqr + sq[cl]);
    d2 = fmaxf(d2, 0.0f);                          // key-safe (sign bit)
    const u64 key = ((u64)__float_as_uint(d2) << 32) | (unsigned)cl;
    if (lane == c) mykey = key;
  }

  // bitonic sort ascending across 64 lanes (lanes >= NCAND hold ~0ull)
#pragma unroll
  for (int k = 2; k <= 64; k <<= 1) {
#pragma unroll
    for (int j = k >> 1; j > 0; j >>= 1) {
      const u64 o = __shfl_xor(mykey, j);
      const bool up = ((lane & k) == 0);
      const bool lower = ((lane & j) == 0);
      const u64 mn = (mykey < o) ? mykey : o;
      const u64 mx = (mykey < o) ? o : mykey;
      mykey = (lower == up) ? mn : mx;
    }
  }

  const size_t ob = ((size_t)which * N + row) * KNN;
  if (lane < KNN) {
    const float d2v = __uint_as_float((unsigned)(mykey >> 32));
    knnd[ob + lane] = (d2v > 0.f) ? sqrtf(fmaxf(d2v, 1e-24f)) : 0.f;
    knni[ob + lane] = (int)(mykey & 0xffffffffu);
  }
}

// ---------------------------------------------------------------- fallback: f32 VALU gram KNN
__global__ __launch_bounds__(256)
void k_knn_fb(const float* __restrict__ Ecur, const float* __restrict__ Eref,
              const float* __restrict__ sqall,
              float* __restrict__ knnd, int* __restrict__ knni)
{
  const int which = blockIdx.y;
  const float* E = which ? Eref : Ecur;
  const float* sq = sqall + which * N;
  float* outd = knnd + (size_t)which * N * KNN;
  int* outi = knni + (size_t)which * N * KNN;
  const int row0 = blockIdx.x * RB;

  __shared__ float As[RB][KB + 1];
  __shared__ float Bs[KB][CB + 4];
  __shared__ float Dtf[RB][CB + 1];
  __shared__ float topv[RB][KNN];
  __shared__ int topi[RB][KNN];

  const int tid = threadIdx.x;
  const int tx = tid & 15, ty = tid >> 4;

  if (tid < RB) {
#pragma unroll
    for (int j = 0; j < KNN; ++j) { topv[tid][j] = INF; topi[tid][j] = -1; }
  }

  for (int ct = 0; ct < N; ct += CB) {
    float acc[2][4] = {{0.f,0.f,0.f,0.f},{0.f,0.f,0.f,0.f}};
    for (int kt = 0; kt < D; kt += KB) {
      __syncthreads();
      {
        int r = tid >> 3, c4 = (tid & 7) << 2;
        const float4 v = *(const float4*)&E[(size_t)(row0 + r) * D + kt + c4];
        As[r][c4+0] = v.x; As[r][c4+1] = v.y; As[r][c4+2] = v.z; As[r][c4+3] = v.w;
      }
      {
        int k = tid & 31, cbase = tid >> 5;
#pragma unroll
        for (int i = 0; i < 8; ++i) {
          int c = cbase + (i << 3);
          Bs[k][c] = E[(size_t)(ct + c) * D + kt + k];
        }
      }
      __syncthreads();
#pragma unroll
      for (int k = 0; k < KB; ++k) {
        float a0 = As[2*ty + 0][k], a1 = As[2*ty + 1][k];
        float4 b = *(const float4*)&Bs[k][tx << 2];
        acc[0][0] = fmaf(a0, b.x, acc[0][0]); acc[0][1] = fmaf(a0, b.y, acc[0][1]);
        acc[0][2] = fmaf(a0, b.z, acc[0][2]); acc[0][3] = fmaf(a0, b.w, acc[0][3]);
        acc[1][0] = fmaf(a1, b.x, acc[1][0]); acc[1][1] = fmaf(a1, b.y, acc[1][1]);
        acc[1][2] = fmaf(a1, b.z, acc[1][2]); acc[1][3] = fmaf(a1, b.w, acc[1][3]);
      }
    }
    {
      float sr0 = sq[row0 + 2*ty + 0], sr1 = sq[row0 + 2*ty + 1];
#pragma unroll
      for (int c = 0; c < 4; ++c) {
        int gc = ct + (tx << 2) + c;
        float scv = sq[gc];
        float d20 = sr0 + scv - 2.0f * acc[0][c];
        float d21 = sr1 + scv - 2.0f * acc[1][c];
        float d0 = (d20 > 0.0f) ? sqrtf(fmaxf(d20, 1e-24f)) : 0.0f;
        float d1 = (d21 > 0.0f) ? sqrtf(fmaxf(d21, 1e-24f)) : 0.0f;
        if (gc == row0 + 2*ty + 0) d0 = INF;
        if (gc == row0 + 2*ty + 1) d1 = INF;
        Dtf[2*ty + 0][(tx << 2) + c] = d0;
        Dtf[2*ty + 1][(tx << 2) + c] = d1;
      }
    }
    __syncthreads();
    if (tid < RB) {
      float kth = topv[tid][KNN-1];
      for (int c = 0; c < CB; ++c) {
        float d = Dtf[tid][c];
        if (d < kth) {
          int gi = ct + c;
          int j = KNN - 1;
          while (j > 0 && topv[tid][j-1] > d) {
            topv[tid][j] = topv[tid][j-1]; topi[tid][j] = topi[tid][j-1]; --j;
          }
          topv[tid][j] = d; topi[tid][j] = gi;
          kth = topv[tid][KNN-1];
        }
      }
    }
    __syncthreads();
  }
  if (tid < RB) {
    int gr = row0 + tid;
#pragma unroll
    for (int j = 0; j < KNN; ++j) {
      outd[(size_t)gr * KNN + j] = topv[tid][j];
      outi[(size_t)gr * KNN + j] = topi[tid][j];
    }
  }
}

// ---------------------------------------------------------------- angular via per-point MFMA gram
__global__ __launch_bounds__(256)
void k_ang3(const float* __restrict__ Ecur, const float* __restrict__ Eref,
            const int* __restrict__ knni, float* __restrict__ angpart)
{
  __shared__ __align__(16) short Vb[16][520];   // 16640 B, pad -> bank-clean frags
  __shared__ float Gp[4][256];
  __shared__ float G[256];
  __shared__ float invn[16];
  __shared__ float cref[NPAIR];
  __shared__ float red2[256];

  const int i = blockIdx.x;
  const int tid = threadIdx.x;
  const int lane = tid & 63;
  const int w = tid >> 6;
  const int base = lane * 8;

  float acc = 0.f;

#pragma unroll 1
  for (int pass = 0; pass < 2; ++pass) {
    const float* E = pass ? Ecur : Eref;
    const int* idx = knni + ((size_t)(pass ? 0 : 1) * N + i) * KNN;

    const float4* er = (const float4*)(E + (size_t)i * D) + lane * 2;
    const float4 e0 = er[0], e1 = er[1];

#pragma unroll 1
    for (int j = w; j < 16; j += 4) {
      u16x8 hv;
      if (j < 15) {
        const float* src = E + (size_t)idx[j] * D;
        const float4 x0 = *(const float4*)(src + base);
        const float4 x1 = *(const float4*)(src + base + 4);
        const float dd[8] = {x0.x-e0.x, x0.y-e0.y, x0.z-e0.z, x0.w-e0.w,
                             x1.x-e1.x, x1.y-e1.y, x1.z-e1.z, x1.w-e1.w};
#pragma unroll
        for (int q = 0; q < 8; ++q) hv[q] = bf16_rne(dd[q]);
      } else {
#pragma unroll
        for (int q = 0; q < 8; ++q) hv[q] = 0;
      }
      *(u16x8*)&Vb[j][base] = hv;
    }
    __syncthreads();

    {
      const int r = lane & 15, fq = lane >> 4;
      f32x4 g = (f32x4){0.f, 0.f, 0.f, 0.f};
#pragma unroll
      for (int s = 0; s < 4; ++s) {
        const s16x8 f = *(const s16x8*)&Vb[r][w * 128 + s * 32 + fq * 8];
        g = __builtin_amdgcn_mfma_f32_16x16x32_bf16(f, f, g, 0, 0, 0);
      }
#pragma unroll
      for (int r2 = 0; r2 < 4; ++r2)
        Gp[w][(fq * 4 + r2) * 16 + r] = g[r2];
    }
    __syncthreads();

    G[tid] = Gp[0][tid] + Gp[1][tid] + Gp[2][tid] + Gp[3][tid];
    __syncthreads();
    if (tid < 16) invn[tid] = 1.0f / fmaxf(sqrtf(G[tid * 17]), 1e-12f);
    __syncthreads();

    if (tid < NPAIR) {
      int a = 0, q = tid, rem = KNN - 1;
      while (q >= rem) { q -= rem; ++a; --rem; }
      const int b = a + 1 + q;
      const float cosv = G[a * 16 + b] * invn[a] * invn[b];
      if (pass == 0) cref[tid] = cosv;
      else { const float dd = cosv - cref[tid]; acc = dd * dd; }
    }
    __syncthreads();
  }

  red2[tid] = acc;
  __syncthreads();
  for (int o = 128; o; o >>= 1) {
    if (tid < o) red2[tid] += red2[tid + o];
    __syncthreads();
  }
  if (tid == 0) angpart[i] = red2[0];
}

// ---------------------------------------------------------------- per-row stats
__global__ __launch_bounds__(256)
void k_stats(const float* __restrict__ knnd, float* __restrict__ dens,
             float* __restrict__ loss1part)
{
  __shared__ float red[256];
  int n = blockIdx.x * 256 + threadIdx.x;
  const float* dc = knnd + (size_t)n * KNN;
  const float* dr = knnd + (size_t)(N + n) * KNN;
  float mc = 0.f, mr = 0.f;
#pragma unroll
  for (int j = 0; j < KNN; ++j) { mc += dc[j]; mr += dr[j]; }
  mc *= (1.0f / KNN); mr *= (1.0f / KNN);
  float ic = 1.0f / (mc + EPSF);
  float ir = 1.0f / (mr + EPSF);
  float s = 0.f;
#pragma unroll
  for (int j = 0; j < KNN; ++j) {
    float t = dc[j] * ic - dr[j] * ir;
    s = fmaf(t, t, s);
  }
  dens[n] = ic;
  dens[N + n] = ir;
  red[threadIdx.x] = s;
  __syncthreads();
  for (int o = 128; o; o >>= 1) {
    if (threadIdx.x < o) red[threadIdx.x] += red[threadIdx.x + o];
    __syncthreads();
  }
  if (threadIdx.x == 0) loss1part[blockIdx.x] = red[0];
}

// ---------------------------------------------------------------- final combine
__global__ __launch_bounds__(256)
void k_final(const float* __restrict__ loss1part, const float* __restrict__ dens,
             const float* __restrict__ angpart, float* __restrict__ out)
{
  __shared__ float red[256];
  const int t = threadIdx.x;

  float sc = 0.f, sr = 0.f;
  for (int n = t; n < N; n += 256) { sc += dens[n]; sr += dens[N + n]; }
  red[t] = sc; __syncthreads();
  for (int o = 128; o; o >>= 1) { if (t < o) red[t] += red[t + o]; __syncthreads(); }
  float scm = red[0]; __syncthreads();
  red[t] = sr; __syncthreads();
  for (int o = 128; o; o >>= 1) { if (t < o) red[t] += red[t + o]; __syncthreads(); }
  float srm = red[0]; __syncthreads();

  float icm = 1.0f / (scm / (float)N + EPSF);
  float irm = 1.0f / (srm / (float)N + EPSF);

  float l2 = 0.f;
  for (int n = t; n < N; n += 256) {
    float dd = dens[n] * icm - dens[N + n] * irm;
    l2 = fmaf(dd, dd, l2);
  }
  red[t] = l2; __syncthreads();
  for (int o = 128; o; o >>= 1) { if (t < o) red[t] += red[t + o]; __syncthreads(); }
  float l2sum = red[0]; __syncthreads();

  float l1 = (t < 32) ? loss1part[t] : 0.f;
  red[t] = l1; __syncthreads();
  for (int o = 128; o; o >>= 1) { if (t < o) red[t] += red[t + o]; __syncthreads(); }
  float l1sum = red[0]; __syncthreads();

  float l3 = 0.f;
  for (int n = t; n < N; n += 256) l3 += angpart[n];
  red[t] = l3; __syncthreads();
  for (int o = 128; o; o >>= 1) { if (t < o) red[t] += red[t + o]; __syncthreads(); }
  float l3sum = red[0];

  if (t == 0) {
    out[0] = l1sum / (float)(N * KNN)
           + 0.5f * l2sum / (float)N
           + 0.5f * l3sum / (float)(N * NPAIR);
  }
}

// ---------------------------------------------------------------- launch
extern "C" void kernel_launch(void* const* d_in, const int* in_sizes, int n_in,
                              void* d_out, int out_size, void* d_ws, size_t ws_size,
                              hipStream_t stream)
{
  const float* emb = (const float*)d_in[0];
  const float* ref = (const float*)d_in[1];
  float* out = (float*)d_out;
  char* ws = (char*)d_ws;

  const size_t off_sq = 0;                                  // 2N f32
  const size_t off_hi = off_sq + (size_t)2 * N * 4;         // 2ND bf16 (hi only)

  const size_t m_off_pk   = off_hi + (size_t)2 * N * D * 2;              // 2*8*N*16 u32
  const size_t m_off_cidx = m_off_pk + (size_t)2 * SPLITS * N * NC * 4;  // 2*N*32 i32
  const size_t m_off_knnd = m_off_cidx + (size_t)2 * N * NCAND * 4;
  const size_t m_off_knni = m_off_knnd + (size_t)2 * N * KNN * 4;
  const size_t m_off_angp = m_off_knni + (size_t)2 * N * KNN * 4;
  const size_t m_off_dens = m_off_angp + (size_t)N * 4;
  const size_t m_off_l1   = m_off_dens + (size_t)2 * N * 4;
  const size_t NEED       = m_off_l1 + 4096;

  float* sq = (float*)(ws + off_sq);
  float* knnd; int* knni; float* angpart; float* dens; float* l1part;

  k_sqnorm<<<(2 * N) / 4, 256, 0, stream>>>(emb, ref, sq);

  if (ws_size >= NEED) {
    unsigned short* hi = (unsigned short*)(ws + off_hi);
    unsigned* pk = (unsigned*)(ws + m_off_pk);
    int* cidx = (int*)(ws + m_off_cidx);
    knnd = (float*)(ws + m_off_knnd);
    knni = (int*)(ws + m_off_knni);
    angpart = (float*)(ws + m_off_angp);
    dens = (float*)(ws + m_off_dens);
    l1part = (float*)(ws + m_off_l1);

    k_split_hi<<<(2 * N * D / 8) / 256, 256, 0, stream>>>(emb, ref, hi);
    k_knn1<<<dim3(N / 128, SPLITS, 2), 256, 0, stream>>>(hi, sq, pk);
    k_cand<<<(2 * N) / 256, 256, 0, stream>>>(pk, cidx);
    k_rescore<<<(2 * N) / 4, 256, 0, stream>>>(emb, ref, sq, cidx, knnd, knni);
  } else {
    size_t o = off_hi;
    knnd = (float*)(ws + o); o += (size_t)2 * N * KNN * 4;
    knni = (int*)(ws + o);   o += (size_t)2 * N * KNN * 4;
    angpart = (float*)(ws + o); o += (size_t)N * 4;
    dens = (float*)(ws + o); o += (size_t)2 * N * 4;
    l1part = (float*)(ws + o);
    k_knn_fb<<<dim3(N / RB, 2), 256, 0, stream>>>(emb, ref, sq, knnd, knni);
  }

  k_ang3<<<N, 256, 0, stream>>>(emb, ref, knni, angpart);
  k_stats<<<N / 256, 256, 0, stream>>>(knnd, dens, l1part);
  k_final<<<1, 256, 0, stream>>>(l1part, dens, angpart, out);
}

// Round 12
// 367.231 us; speedup vs baseline: 3.6605x; 1.0786x over previous
//
#include <hip/hip_runtime.h>

#define N 8192
#define D 512
#define KNN 15
#define SC 8       // per-scanner register list
#define NC 16      // per-split candidate list (2 scanners merged)
#define SPLITS 8
#define NCAND 32   // rescored candidates per row
#define NPAIR 105
#define EPSF 1e-8f

#define INF __int_as_float(0x7f800000)

typedef __attribute__((ext_vector_type(4))) float f32x4;
typedef __attribute__((ext_vector_type(4))) unsigned u32x4;
typedef __attribute__((ext_vector_type(8))) short s16x8;
typedef __attribute__((ext_vector_type(8))) unsigned short u16x8;
typedef unsigned long long u64;

typedef const unsigned int __attribute__((address_space(1)))* gp_t;
typedef unsigned int __attribute__((address_space(3)))* lp_t;

__device__ __forceinline__ void gl_lds16(const void* g, void* l) {
  __builtin_amdgcn_global_load_lds((gp_t)g, (lp_t)l, 16, 0, 0);
}

__device__ __forceinline__ unsigned short bf16_rne(float x) {
  unsigned int u = __float_as_uint(x);
  return (unsigned short)((u + 0x7fffu + ((u >> 16) & 1u)) >> 16);
}

#define VMCNT4 asm volatile("s_waitcnt vmcnt(4)" ::: "memory")
#define VMCNT0 asm volatile("s_waitcnt vmcnt(0)" ::: "memory")
#define LGKM0  asm volatile("s_waitcnt lgkmcnt(0)" ::: "memory")
#define CFENCE asm volatile("" ::: "memory")

// ---------------------------------------------------------------- fused sq-norms + bf16 cast (one input pass)
__global__ __launch_bounds__(256)
void k_prep(const float* __restrict__ A, const float* __restrict__ B,
            unsigned short* __restrict__ hi, float* __restrict__ sq)
{
  const int tid = threadIdx.x;
  const int lane = tid & 63;
  const int row = blockIdx.x * 4 + (tid >> 6);    // 0 .. 2N-1
  const float* src = (row < N) ? (A + (size_t)row * D)
                               : (B + (size_t)(row - N) * D);
  const float4* s4 = (const float4*)src + lane * 2;
  const float4 x0 = s4[0], x1 = s4[1];
  const float xs[8] = {x0.x, x0.y, x0.z, x0.w, x1.x, x1.y, x1.z, x1.w};
  u16x8 hv;
  float s = 0.f;
#pragma unroll
  for (int j = 0; j < 8; ++j) {
    hv[j] = bf16_rne(xs[j]);
    s = fmaf(xs[j], xs[j], s);
  }
  *(u16x8*)(hi + (size_t)row * D + lane * 8) = hv;
#pragma unroll
  for (int o = 32; o; o >>= 1) s += __shfl_xor(s, o);
  if (lane == 0) sq[row] = s;
}

// ================================================================ stage 1:
// approx (hi-only) MFMA gram + per-split top-16 candidate KEYS.
// key u32 = (f32bits(max(d2,0)) & ~8191) | global_col  (col < 8192, 13 bits).
// Producer writes KEYS into the LDS tile (self -> 0xFFFFFFFF); scanner is
// load+compare only. 8 column splits -> 1024 blocks -> 4 blocks/CU.
__global__ __launch_bounds__(256, 4)
void k_knn1(const unsigned short* __restrict__ hi,
            const float* __restrict__ sqall,
            unsigned* __restrict__ pk)
{
  __shared__ __align__(16) char smem[40960];
  unsigned* DtU = (unsigned*)smem;          // [128][68] key tile
  unsigned* SK = (unsigned*)smem;           // [128][16] merge overlay

  const int tid = threadIdx.x;
  const int lane = tid & 63, w = tid >> 6;
  const int wr = w >> 1, wc = w & 1;
  const int fr = lane & 15, fq = lane >> 4;
  const int sgx = fq ^ ((fr >> 1) & 3);     // read-side seg swizzle

  const int rb = blockIdx.x, split = blockIdx.y, which = blockIdx.z;
  const int row0 = rb * 128;
  const int c0 = split * 1024;
  const unsigned short* Hi = hi + (size_t)which * N * D;
  const float* sq = sqall + which * N;

  const int rr = tid >> 2, sseg = tid & 3;
  const int ssg = sseg ^ ((rr >> 1) & 3);
  const unsigned short* pAh = Hi + (size_t)(row0 + rr) * D + ssg * 8;
  const unsigned short* pBh = Hi + (size_t)(c0 + rr) * D + ssg * 8;

  auto stage = [&](int sel) {
    char* d = smem + (sel << 14) + (w << 10);   // wave-uniform dest base
    gl_lds16(pAh, d);
    gl_lds16(pAh + 32768, d + 4096);            // rows +64 (+65536 B global)
    gl_lds16(pBh, d + 8192);
    gl_lds16(pBh + 32768, d + 12288);
    pAh += 32; pBh += 32;                        // next K-step
  };

  const int srow = tid >> 1, ssub = tid & 1;
  unsigned tv[SC];
#pragma unroll
  for (int j = 0; j < SC; ++j) tv[j] = 0xFFFFFFFFu;

  float sqr[4][4];
#pragma unroll
  for (int m = 0; m < 4; ++m)
#pragma unroll
    for (int j = 0; j < 4; ++j)
      sqr[m][j] = sq[row0 + wr * 64 + m * 16 + fq * 4 + j];

#pragma unroll 1
  for (int t = 0; t < 8; ++t) {
    const int ct = c0 + t * 128;
    float sqc[4];
#pragma unroll
    for (int n = 0; n < 4; ++n) sqc[n] = sq[ct + wc * 64 + n * 16 + fr];

    f32x4 acc[4][4];
#pragma unroll
    for (int m = 0; m < 4; ++m)
#pragma unroll
      for (int n = 0; n < 4; ++n) acc[m][n] = (f32x4){0.f, 0.f, 0.f, 0.f};

    stage(0);
    int cur = 0;
#pragma unroll 1
    for (int kt = 0; kt < 16; ++kt) {
      if (kt < 15) {
        stage(cur ^ 1);   // 8 outstanding
        VMCNT4;           // own 4 oldest = buf[cur] loads complete
      } else {
        VMCNT0;
      }
      __builtin_amdgcn_s_barrier();
      CFENCE;

      const short* Sb = (const short*)(smem + (cur << 14));
      s16x8 ah[4], bh[4];
#pragma unroll
      for (int m = 0; m < 4; ++m)
        ah[m] = *(const s16x8*)(Sb + (wr * 64 + m * 16 + fr) * 32 + sgx * 8);
#pragma unroll
      for (int n = 0; n < 4; ++n)
        bh[n] = *(const s16x8*)(Sb + 4096 + (wc * 64 + n * 16 + fr) * 32 + sgx * 8);
#pragma unroll
      for (int m = 0; m < 4; ++m)
#pragma unroll
        for (int n = 0; n < 4; ++n)
          acc[m][n] = __builtin_amdgcn_mfma_f32_16x16x32_bf16(ah[m], bh[n], acc[m][n], 0, 0, 0);

      LGKM0;
      __builtin_amdgcn_s_barrier();
      CFENCE;
      cur ^= 1;
    }
    pAh -= 512; pBh += 65024;

    // ---- epilogue: producer writes u32 KEYS; scanner = load + cmp + insert
#pragma unroll 1
    for (int h = 0; h < 2; ++h) {
      if (wc == h) {
#pragma unroll
        for (int m = 0; m < 4; ++m)
#pragma unroll
          for (int n = 0; n < 4; ++n) {
            const int cl = n * 16 + fr;
            const int gcol = ct + h * 64 + cl;
            const int rbase = wr * 64 + m * 16 + fq * 4;
#pragma unroll
            for (int j = 0; j < 4; ++j) {
              const float d2 = fmaf(-2.0f, acc[m][n][j], sqr[m][j] + sqc[n]);
              unsigned key = (__float_as_uint(fmaxf(d2, 0.f)) & ~8191u) | (unsigned)gcol;
              if (row0 + rbase + j == gcol) key = 0xFFFFFFFFu;   // exclude self
              DtU[(rbase + j) * 68 + cl] = key;
            }
          }
      }
      __syncthreads();
      {
        unsigned kth = tv[SC - 1];
#pragma unroll 1
        for (int g = 0; g < 8; ++g) {
          const u32x4 dv = *(const u32x4*)&DtU[srow * 68 + ssub * 32 + g * 4];
#pragma unroll
          for (int i = 0; i < 4; ++i) {
            unsigned key = dv[i];
            if (key < kth) {
#pragma unroll
              for (int j = 0; j < SC; ++j) {
                const unsigned lo = min(tv[j], key);
                key = max(tv[j], key);
                tv[j] = lo;
              }
              kth = tv[SC - 1];
            }
          }
        }
      }
      __syncthreads();
    }
  }

  // ---- block end: merge 2 sorted scanner lists per row -> sorted top-16 keys
#pragma unroll
  for (int j = 0; j < SC; ++j) SK[srow * 16 + ssub * 8 + j] = tv[j];
  __syncthreads();
  if (tid < 128) {
    const int grow = row0 + tid;
    const size_t pb = (((size_t)which * SPLITS + split) * N + grow) * NC;
    int p0 = 0, p1 = 0;
#pragma unroll
    for (int j = 0; j < NC; ++j) {
      const unsigned a = (p0 < SC) ? SK[tid * 16 + p0] : 0xFFFFFFFFu;
      const unsigned b = (p1 < SC) ? SK[tid * 16 + 8 + p1] : 0xFFFFFFFFu;
      const bool ta = a <= b;
      pk[pb + j] = ta ? a : b;
      if (ta) ++p0; else ++p1;
    }
  }
}

// ================================================================ fused tail:
// per point i: rescore ref (wave 0) + cur (wave 1) via bitonic-128 candidate
// merge -> exact f32 top-15; in-LDS handoff; per-point stats; MFMA angular.
__global__ __launch_bounds__(256)
void k_tail(const float* __restrict__ emb, const float* __restrict__ ref,
            const float* __restrict__ sqall, const unsigned* __restrict__ pk,
            float* __restrict__ dens, float* __restrict__ l1p,
            float* __restrict__ angp)
{
  __shared__ __align__(16) short Vb[16][520];
  __shared__ float Gp[4][256];
  __shared__ float G[256];
  __shared__ float invn[16];
  __shared__ float cref[NPAIR];
  __shared__ float red2[256];
  __shared__ int idxs[2][16];      // [0]=ref neighbors, [1]=cur
  __shared__ float dls[2][16];

  const int i = blockIdx.x;
  const int tid = threadIdx.x;
  const int lane = tid & 63;
  const int w = tid >> 6;

  // ---- Phase A: waves 0 (ref, which=1) and 1 (cur, which=0) rescore
  if (w < 2) {
    const int which = 1 - w;
    const float* E = which ? ref : emb;
    const float* sqm = sqall + which * N;

    // load 128 candidate keys (8 splits x 16), 2 per lane
    const int sp = lane >> 3, jj = lane & 7;
    const size_t kb = (((size_t)which * SPLITS + sp) * N + i) * NC;
    unsigned v0 = pk[kb + jj];
    unsigned v1 = pk[kb + 8 + jj];

    // bitonic sort 128 ascending; element g: g<64 -> v0[lane g], g>=64 -> v1[lane g-64]
#pragma unroll
    for (int k = 2; k <= 128; k <<= 1) {
#pragma unroll
      for (int s = k >> 1; s > 0; s >>= 1) {
        if (s == 64) {                       // only at k=128; pair (v0,v1), ascending
          const unsigned mn = min(v0, v1), mx = max(v0, v1);
          v0 = mn; v1 = mx;
        } else {
          const unsigned o0 = __shfl_xor(v0, s);
          const unsigned o1 = __shfl_xor(v1, s);
          const bool low = ((lane & s) == 0);
          const bool dir0 = ((lane & k) == 0);          // g = lane
          const bool dir1 = (((64 + lane) & k) == 0);   // g = 64+lane
          const unsigned a0 = min(v0, o0), b0 = max(v0, o0);
          v0 = (low == dir0) ? a0 : b0;
          const unsigned a1 = min(v1, o1), b1 = max(v1, o1);
          v1 = (low == dir1) ? a1 : b1;
        }
      }
    }
    // candidates = 32 smallest = v0 of lanes 0..31

    const float4* orow = (const float4*)(E + (size_t)i * D) + lane * 2;
    const float4 o0 = orow[0], o1 = orow[1];
    const float sqr_ = sqm[i];

    u64 mykey = ~0ull;
#pragma unroll 4
    for (int c = 0; c < NCAND; ++c) {
      const int cl = (int)(__shfl(v0, c) & 8191u);
      const float4* crow = (const float4*)(E + (size_t)cl * D) + lane * 2;
      const float4 c0 = crow[0], c1 = crow[1];
      float s = o0.x*c0.x + o0.y*c0.y + o0.z*c0.z + o0.w*c0.w
              + o1.x*c1.x + o1.y*c1.y + o1.z*c1.z + o1.w*c1.w;
#pragma unroll
      for (int o = 32; o; o >>= 1) s += __shfl_xor(s, o);
      float d2 = fmaf(-2.0f, s, sqr_ + sqm[cl]);
      d2 = fmaxf(d2, 0.0f);
      const u64 key = ((u64)__float_as_uint(d2) << 32) | (unsigned)cl;
      if (lane == c) mykey = key;
    }

    // bitonic sort ascending across 64 lanes (lanes >= NCAND hold ~0ull)
#pragma unroll
    for (int k = 2; k <= 64; k <<= 1) {
#pragma unroll
      for (int j = k >> 1; j > 0; j >>= 1) {
        const u64 o = __shfl_xor(mykey, j);
        const bool up = ((lane & k) == 0);
        const bool lower = ((lane & j) == 0);
        const u64 mn = (mykey < o) ? mykey : o;
        const u64 mx = (mykey < o) ? o : mykey;
        mykey = (lower == up) ? mn : mx;
      }
    }

    if (lane < KNN) {
      const float d2v = __uint_as_float((unsigned)(mykey >> 32));
      dls[w][lane] = (d2v > 0.f) ? sqrtf(fmaxf(d2v, 1e-24f)) : 0.f;
      idxs[w][lane] = (int)(mykey & 0xffffffffu);
    }
  }
  __syncthreads();

  // ---- Phase A2: per-point stats (dls[0]=ref, dls[1]=cur)
  if (tid == 0) {
    float mr = 0.f, mc = 0.f;
#pragma unroll
    for (int j = 0; j < KNN; ++j) { mr += dls[0][j]; mc += dls[1][j]; }
    mr *= (1.0f / KNN); mc *= (1.0f / KNN);
    const float ir = 1.0f / (mr + EPSF);
    const float ic = 1.0f / (mc + EPSF);
    float s1 = 0.f;
#pragma unroll
    for (int j = 0; j < KNN; ++j) {
      const float t = dls[1][j] * ic - dls[0][j] * ir;
      s1 = fmaf(t, t, s1);
    }
    dens[i] = ic;
    dens[N + i] = ir;
    l1p[i] = s1;
  }
  __syncthreads();

  // ---- Phase B: angular via per-point MFMA gram (pass 0 = ref, 1 = cur)
  const int base = lane * 8;
  float acc = 0.f;

#pragma unroll 1
  for (int pass = 0; pass < 2; ++pass) {
    const float* E = pass ? emb : ref;

    const float4* er = (const float4*)(E + (size_t)i * D) + lane * 2;
    const float4 e0 = er[0], e1 = er[1];

#pragma unroll 1
    for (int j = w; j < 16; j += 4) {
      u16x8 hv;
      if (j < 15) {
        const float* src = E + (size_t)idxs[pass][j] * D;
        const float4 x0 = *(const float4*)(src + base);
        const float4 x1 = *(const float4*)(src + base + 4);
        const float dd[8] = {x0.x-e0.x, x0.y-e0.y, x0.z-e0.z, x0.w-e0.w,
                             x1.x-e1.x, x1.y-e1.y, x1.z-e1.z, x1.w-e1.w};
#pragma unroll
        for (int q = 0; q < 8; ++q) hv[q] = bf16_rne(dd[q]);
      } else {
#pragma unroll
        for (int q = 0; q < 8; ++q) hv[q] = 0;
      }
      *(u16x8*)&Vb[j][base] = hv;
    }
    __syncthreads();

    {
      const int r = lane & 15, fq = lane >> 4;
      f32x4 g = (f32x4){0.f, 0.f, 0.f, 0.f};
#pragma unroll
      for (int s = 0; s < 4; ++s) {
        const s16x8 f = *(const s16x8*)&Vb[r][w * 128 + s * 32 + fq * 8];
        g = __builtin_amdgcn_mfma_f32_16x16x32_bf16(f, f, g, 0, 0, 0);
      }
#pragma unroll
      for (int r2 = 0; r2 < 4; ++r2)
        Gp[w][(fq * 4 + r2) * 16 + r] = g[r2];
    }
    __syncthreads();

    G[tid] = Gp[0][tid] + Gp[1][tid] + Gp[2][tid] + Gp[3][tid];
    __syncthreads();
    if (tid < 16) invn[tid] = 1.0f / fmaxf(sqrtf(G[tid * 17]), 1e-12f);
    __syncthreads();

    if (tid < NPAIR) {
      int a = 0, q = tid, rem = KNN - 1;
      while (q >= rem) { q -= rem; ++a; --rem; }
      const int b = a + 1 + q;
      const float cosv = G[a * 16 + b] * invn[a] * invn[b];
      if (pass == 0) cref[tid] = cosv;
      else { const float dd = cosv - cref[tid]; acc = dd * dd; }
    }
    __syncthreads();
  }

  red2[tid] = acc;
  __syncthreads();
  for (int o = 128; o; o >>= 1) {
    if (tid < o) red2[tid] += red2[tid + o];
    __syncthreads();
  }
  if (tid == 0) angp[i] = red2[0];
}

// ---------------------------------------------------------------- final combine
__global__ __launch_bounds__(256)
void k_final(const float* __restrict__ l1p, const float* __restrict__ dens,
             const float* __restrict__ angp, float* __restrict__ out)
{
  __shared__ float red[256];
  const int t = threadIdx.x;

  float sc = 0.f, sr = 0.f;
  for (int n = t; n < N; n += 256) { sc += dens[n]; sr += dens[N + n]; }
  red[t] = sc; __syncthreads();
  for (int o = 128; o; o >>= 1) { if (t < o) red[t] += red[t + o]; __syncthreads(); }
  float scm = red[0]; __syncthreads();
  red[t] = sr; __syncthreads();
  for (int o = 128; o; o >>= 1) { if (t < o) red[t] += red[t + o]; __syncthreads(); }
  float srm = red[0]; __syncthreads();

  const float icm = 1.0f / (scm / (float)N + EPSF);
  const float irm = 1.0f / (srm / (float)N + EPSF);

  float l2 = 0.f;
  for (int n = t; n < N; n += 256) {
    const float dd = dens[n] * icm - dens[N + n] * irm;
    l2 = fmaf(dd, dd, l2);
  }
  red[t] = l2; __syncthreads();
  for (int o = 128; o; o >>= 1) { if (t < o) red[t] += red[t + o]; __syncthreads(); }
  const float l2sum = red[0]; __syncthreads();

  float l1 = 0.f;
  for (int n = t; n < N; n += 256) l1 += l1p[n];
  red[t] = l1; __syncthreads();
  for (int o = 128; o; o >>= 1) { if (t < o) red[t] += red[t + o]; __syncthreads(); }
  const float l1sum = red[0]; __syncthreads();

  float l3 = 0.f;
  for (int n = t; n < N; n += 256) l3 += angp[n];
  red[t] = l3; __syncthreads();
  for (int o = 128; o; o >>= 1) { if (t < o) red[t] += red[t + o]; __syncthreads(); }
  const float l3sum = red[0];

  if (t == 0) {
    out[0] = l1sum / (float)(N * KNN)
           + 0.5f * l2sum / (float)N
           + 0.5f * l3sum / (float)(N * NPAIR);
  }
}

// ---------------------------------------------------------------- launch
extern "C" void kernel_launch(void* const* d_in, const int* in_sizes, int n_in,
                              void* d_out, int out_size, void* d_ws, size_t ws_size,
                              hipStream_t stream)
{
  const float* emb = (const float*)d_in[0];
  const float* ref = (const float*)d_in[1];
  float* out = (float*)d_out;
  char* ws = (char*)d_ws;

  const size_t off_sq   = 0;                                            // 2N f32
  const size_t off_hi   = off_sq + (size_t)2 * N * 4;                   // 2ND bf16
  const size_t off_pk   = off_hi + (size_t)2 * N * D * 2;               // 2*8*N*16 u32
  const size_t off_dens = off_pk + (size_t)2 * SPLITS * N * NC * 4;     // 2N f32
  const size_t off_l1   = off_dens + (size_t)2 * N * 4;                 // N f32
  const size_t off_ang  = off_l1 + (size_t)N * 4;                       // N f32

  float* sq = (float*)(ws + off_sq);
  unsigned short* hi = (unsigned short*)(ws + off_hi);
  unsigned* pk = (unsigned*)(ws + off_pk);
  float* dens = (float*)(ws + off_dens);
  float* l1p = (float*)(ws + off_l1);
  float* angp = (float*)(ws + off_ang);

  k_prep<<<(2 * N) / 4, 256, 0, stream>>>(emb, ref, hi, sq);
  k_knn1<<<dim3(N / 128, SPLITS, 2), 256, 0, stream>>>(hi, sq, pk);
  k_tail<<<N, 256, 0, stream>>>(emb, ref, sq, pk, dens, l1p, angp);
  k_final<<<1, 256, 0, stream>>>(l1p, dens, angp, out);
}